// Round 1
// baseline (1367.317 us; speedup 1.0000x reference)
//
#include <hip/hip_runtime.h>
#include <hip/hip_bf16.h>
#include <math.h>

typedef __hip_bfloat16 bf16;

#define NN 16
#define CCH 256
#define HH 56
#define WW 56
#define SSP 3136        // H*W
#define GG 8
#define GPH 16          // GP/2
#define GPF 32          // GP
#define OCT 512         // q(128)+k(128)+v(256)
#define RL 111          // 2*KS-1
#define EPSV 1e-5f
#define CNT_PROJ 50176.0f   // 896*56 (= 16*3136)
#define CNT_SIM  2809856.0f // 896*56*56

__device__ __forceinline__ float bf2f(bf16 v){ return __bfloat162float(v); }
__device__ __forceinline__ bf16 f2bf(float v){ return __float2bfloat16(v); }

// ---- f32 workspace region layout (float indices) ----
#define F_PR 0
#define F_PD 4096
#define F_SR 8192
#define F_SD 12288
#define F_PSUM 16384
#define F_PSQ  16896
#define F_PA   17408
#define F_PB   17920
#define F_SSUM 18432
#define F_SSQ  18464
#define F_SA   18496
#define F_SB   18528
#define F_OSUM 18560
#define F_OSQ  19072
#define F_OA   19584
#define F_OB   20096
#define F_TOT  20608

// K1: per-(n,c) spatial means of x and x_depth
__global__ __launch_bounds__(256) void k_meanpool(const float* __restrict__ x,
                                                  const float* __restrict__ xd,
                                                  float* __restrict__ fws){
  int nc = blockIdx.x;
  const float* px  = x  + (size_t)nc*SSP;
  const float* pxd = xd + (size_t)nc*SSP;
  float s1=0.f, s2=0.f;
  for(int i=threadIdx.x;i<SSP;i+=256){ s1+=px[i]; s2+=pxd[i]; }
  __shared__ float r1[256], r2[256];
  int t=threadIdx.x;
  r1[t]=s1; r2[t]=s2; __syncthreads();
  for(int st=128;st>0;st>>=1){ if(t<st){ r1[t]+=r1[t+st]; r2[t]+=r2[t+st]; } __syncthreads(); }
  if(t==0){ fws[F_PR+nc]=r1[0]*(1.f/SSP); fws[F_PD+nc]=r2[0]*(1.f/SSP); }
}

// K2: channel attention -> per-(n,c) scale factors sr, sd
__global__ __launch_bounds__(256) void k_chanatt(const float* __restrict__ wr, const float* __restrict__ br,
                                                 const float* __restrict__ wd, const float* __restrict__ bd,
                                                 float* __restrict__ fws){
  int c = threadIdx.x;
  __shared__ float red[256];
  __shared__ float prl[256], pdl[256];
  for(int n=0;n<NN;n++){
    prl[c]=fws[F_PR+n*CCH+c]; pdl[c]=fws[F_PD+n*CCH+c];
    __syncthreads();
    float dr=br[c], dd=bd[c];
    for(int k=0;k<CCH;k++){ dr = fmaf(prl[k], wr[c*CCH+k], dr); dd = fmaf(pdl[k], wd[c*CCH+k], dd); }
    dr = fmaxf(dr,0.f); dd = fmaxf(dd,0.f);
    float car = 1.f/(1.f+expf(-dr));
    float cad = 1.f/(1.f+expf(-dd));
    float tv = car+cad;
    red[c]=tv; __syncthreads();
    for(int st=128;st>0;st>>=1){ if(c<st) red[c]=fmaxf(red[c],red[c+st]); __syncthreads(); }
    float mx = red[0]; __syncthreads();
    float e = expf(tv-mx);
    red[c]=e; __syncthreads();
    for(int st=128;st>0;st>>=1){ if(c<st) red[c]+=red[c+st]; __syncthreads(); }
    float co = e/red[0]; __syncthreads();
    fws[F_SR+n*CCH+c] = co+car;
    fws[F_SD+n*CCH+c] = co+cad;
  }
}

// K3: fused projection GEMM (q,k,v) with on-the-fly input scaling.
// proj layout: [n][o (0..511)][s=h*56+w] bf16. Also accumulates per-o sum/sumsq.
__global__ __launch_bounds__(256) void k_proj(const float* __restrict__ x, const float* __restrict__ xd,
    const float* __restrict__ qw, const float* __restrict__ kw, const float* __restrict__ vw,
    float* __restrict__ fws, bf16* __restrict__ proj){
  int n = blockIdx.z;
  int zo = blockIdx.y;            // 0..7 -> 64-channel output tile
  int s0 = blockIdx.x*128;
  int o0 = zo*64;
  int variant = (zo<2)?0:((zo<4)?1:2);
  const float* Wm = (variant==0)? qw : ((variant==1)? kw : vw);
  int obase = (variant==0)?0:((variant==1)?128:256);
  __shared__ __align__(16) float xs[32][128];
  __shared__ float wt[64][33];
  int t = threadIdx.x;
  int sl = t & 31;                // 32 s-groups of 4
  int og = t >> 5;                // 8 o-groups
  float acc[8][4];
  #pragma unroll
  for(int m=0;m<8;m++){
    #pragma unroll
    for(int u=0;u<4;u++) acc[m][u]=0.f;
  }
  const float* srp = fws + F_SR + n*CCH;
  const float* sdp = fws + F_SD + n*CCH;
  for(int cc=0; cc<CCH; cc+=32){
    for(int idx=t; idx<32*128; idx+=256){
      int ci = idx>>7, si = idx&127;
      int s = s0+si;
      float v=0.f;
      if(s<SSP){
        size_t gi = ((size_t)n*CCH + (cc+ci))*SSP + s;
        if(variant==0) v = x[gi]*srp[cc+ci];
        else if(variant==1) v = xd[gi]*sdp[cc+ci];
        else v = x[gi]*xd[gi];
      }
      xs[ci][si]=v;
    }
    for(int idx=t; idx<64*32; idx+=256){
      int ol = idx>>5, ci = idx&31;
      wt[ol][ci] = Wm[(size_t)(o0-obase+ol)*CCH + (cc+ci)];
    }
    __syncthreads();
    #pragma unroll 4
    for(int ci=0;ci<32;ci++){
      float4 xv = *(const float4*)(&xs[ci][sl*4]);
      #pragma unroll
      for(int m=0;m<8;m++){
        float wv = wt[og+8*m][ci];
        acc[m][0] = fmaf(wv, xv.x, acc[m][0]);
        acc[m][1] = fmaf(wv, xv.y, acc[m][1]);
        acc[m][2] = fmaf(wv, xv.z, acc[m][2]);
        acc[m][3] = fmaf(wv, xv.w, acc[m][3]);
      }
    }
    __syncthreads();
  }
  // stats (padded s contributed exactly 0 -> harmless) + bf16 writeback
  #pragma unroll
  for(int m=0;m<8;m++){
    int o = o0 + og + 8*m;
    float s1 = acc[m][0]+acc[m][1]+acc[m][2]+acc[m][3];
    float s2 = acc[m][0]*acc[m][0]+acc[m][1]*acc[m][1]+acc[m][2]*acc[m][2]+acc[m][3]*acc[m][3];
    #pragma unroll
    for(int msk=1;msk<32;msk<<=1){ s1 += __shfl_xor(s1,msk); s2 += __shfl_xor(s2,msk); }
    if(sl==0){ atomicAdd(&fws[F_PSUM+o], s1); atomicAdd(&fws[F_PSQ+o], s2); }
    #pragma unroll
    for(int u=0;u<4;u++){
      int s = s0 + sl*4 + u;
      if(s<SSP) proj[((size_t)n*OCT+o)*SSP + s] = f2bf(acc[m][u]);
    }
  }
}

// K4: finalize proj BN -> a,b per channel
__global__ void k_finproj(const float* qg,const float* qb,const float* kg,const float* kb,
                          const float* vg,const float* vb, float* fws){
  int o = threadIdx.x;
  float m = fws[F_PSUM+o]*(1.0f/CNT_PROJ);
  float var = fws[F_PSQ+o]*(1.0f/CNT_PROJ) - m*m;
  float g,b;
  if(o<128){ g=qg[o]; b=qb[o]; }
  else if(o<256){ g=kg[o-128]; b=kb[o-128]; }
  else { g=vg[o-256]; b=vb[o-256]; }
  float a = g*rsqrtf(var+EPSV);
  fws[F_PA+o]=a; fws[F_PB+o]=b-m*a;
}

// K5: pass A — sim BN statistics over qk/qr/kr, per channel (which*8+g)
__global__ __launch_bounds__(256) void k_passA(const bf16* __restrict__ proj,
                                               const float* __restrict__ rel,
                                               float* __restrict__ fws){
  int g = blockIdx.x, w = blockIdx.y, n = blockIdx.z;
  __shared__ float qs[GPH][57], ks[GPH][57];
  __shared__ float rq[GPH][RL], rk[GPH][RL];
  __shared__ float red[256];
  int t = threadIdx.x;
  const float* PA = fws+F_PA;
  const float* PB = fws+F_PB;
  for(int idx=t; idx<GPH*HH; idx+=256){
    int c = idx/HH, i = idx-c*HH;
    int oq = g*GPH+c, ok = 128+g*GPH+c;
    qs[c][i] = PA[oq]*bf2f(proj[((size_t)n*OCT+oq)*SSP + i*WW + w]) + PB[oq];
    ks[c][i] = PA[ok]*bf2f(proj[((size_t)n*OCT+ok)*SSP + i*WW + w]) + PB[ok];
  }
  for(int idx=t; idx<GPH*RL; idx+=256){
    int c = idx/RL, r = idx-c*RL;
    rq[c][r] = rel[c*RL+r];
    rk[c][r] = rel[(GPH+c)*RL+r];
  }
  __syncthreads();
  float s1=0,s2=0,s3=0,s4=0,s5=0,s6=0;
  for(int pos=t; pos<SSP; pos+=256){
    int i = pos/HH, j = pos-i*HH;
    float a1=0,a2=0,a3=0;
    #pragma unroll
    for(int c=0;c<GPH;c++){
      float qv=qs[c][i], kv=ks[c][j];
      a1 = fmaf(qv,kv,a1);
      a2 = fmaf(qv, rq[c][i-j+55], a2);
      a3 = fmaf(kv, rk[c][j-i+55], a3);
    }
    s1+=a1; s2+=a1*a1; s3+=a2; s4+=a2*a2; s5+=a3; s6+=a3*a3;
  }
  float vals[6]={s1,s2,s3,s4,s5,s6};
  float outv[6];
  for(int q2=0;q2<6;q2++){
    red[t]=vals[q2]; __syncthreads();
    for(int st=128;st>0;st>>=1){ if(t<st) red[t]+=red[t+st]; __syncthreads(); }
    outv[q2]=red[0]; __syncthreads();
  }
  if(t==0){
    atomicAdd(&fws[F_SSUM+g],    outv[0]); atomicAdd(&fws[F_SSQ+g],    outv[1]);
    atomicAdd(&fws[F_SSUM+8+g],  outv[2]); atomicAdd(&fws[F_SSQ+8+g],  outv[3]);
    atomicAdd(&fws[F_SSUM+16+g], outv[4]); atomicAdd(&fws[F_SSQ+16+g], outv[5]);
  }
}

// K6: finalize sim BN
__global__ void k_finsim(const float* sg, const float* sb, float* fws){
  int ch = threadIdx.x; if(ch>=24) return;
  float m = fws[F_SSUM+ch]*(1.0f/CNT_SIM);
  float var = fws[F_SSQ+ch]*(1.0f/CNT_SIM) - m*m;
  float a = sg[ch]*rsqrtf(var+EPSV);
  fws[F_SA+ch]=a; fws[F_SB+ch]=sb[ch]-m*a;
}

// K7: pass B — recompute ss, softmax, sv/sve + out BN statistics
__global__ __launch_bounds__(256) void k_passB(const bf16* __restrict__ proj,
                                               const float* __restrict__ rel,
                                               float* __restrict__ fws,
                                               bf16* __restrict__ svw, bf16* __restrict__ svew){
  int g = blockIdx.x, w = blockIdx.y, n = blockIdx.z;
  __shared__ float qs[GPH][57], ks[GPH][57], vs[GPF][57];
  __shared__ float rq[GPH][RL], rk[GPH][RL], rv[GPF][RL];
  __shared__ float ssl[HH][57];
  __shared__ float ost[GPF][4];
  int t = threadIdx.x;
  const float* PA = fws+F_PA; const float* PB = fws+F_PB;
  for(int idx=t; idx<GPH*HH; idx+=256){
    int c = idx/HH, i = idx-c*HH;
    int oq = g*GPH+c, ok = 128+g*GPH+c;
    qs[c][i] = PA[oq]*bf2f(proj[((size_t)n*OCT+oq)*SSP + i*WW + w]) + PB[oq];
    ks[c][i] = PA[ok]*bf2f(proj[((size_t)n*OCT+ok)*SSP + i*WW + w]) + PB[ok];
  }
  for(int idx=t; idx<GPF*HH; idx+=256){
    int c = idx/HH, i = idx-c*HH;
    int ov = 256+g*GPF+c;
    vs[c][i] = PA[ov]*bf2f(proj[((size_t)n*OCT+ov)*SSP + i*WW + w]) + PB[ov];
  }
  for(int idx=t; idx<GPH*RL; idx+=256){
    int c = idx/RL, r = idx-c*RL;
    rq[c][r] = rel[c*RL+r];
    rk[c][r] = rel[(GPH+c)*RL+r];
  }
  for(int idx=t; idx<GPF*RL; idx+=256){
    int c = idx/RL, r = idx-c*RL;
    rv[c][r] = rel[(2*GPH+c)*RL+r];
  }
  float aqk=fws[F_SA+g], aqr=fws[F_SA+8+g], akr=fws[F_SA+16+g];
  float bsum=fws[F_SB+g]+fws[F_SB+8+g]+fws[F_SB+16+g];
  __syncthreads();
  for(int pos=t; pos<SSP; pos+=256){
    int i = pos/HH, j = pos-i*HH;
    float a1=0,a2=0,a3=0;
    #pragma unroll
    for(int c=0;c<GPH;c++){
      float qv=qs[c][i], kv=ks[c][j];
      a1=fmaf(qv,kv,a1); a2=fmaf(qv,rq[c][i-j+55],a2); a3=fmaf(kv,rk[c][j-i+55],a3);
    }
    ssl[i][j] = aqk*a1+aqr*a2+akr*a3+bsum;
  }
  __syncthreads();
  // softmax over j per row i, one wave per row
  int wv = t>>6, lane = t&63;
  for(int i=wv; i<HH; i+=4){
    float v = (lane<HH)? ssl[i][lane] : -3.0e38f;
    float m=v;
    #pragma unroll
    for(int msk=32;msk>=1;msk>>=1) m=fmaxf(m,__shfl_xor(m,msk));
    float e = (lane<HH)? expf(v-m) : 0.f;
    float ssum=e;
    #pragma unroll
    for(int msk=32;msk>=1;msk>>=1) ssum+=__shfl_xor(ssum,msk);
    if(lane<HH) ssl[i][lane]=e/ssum;
  }
  __syncthreads();
  // sv / sve: 8-thread group per channel c, each handles 7 rows i
  int c = t>>3, li = t&7;
  float p0=0,p1=0,p2=0,p3=0;
  size_t base = (((size_t)(n*WW+w)*GG+g)*GPF+c)*HH;
  for(int kk=0;kk<7;kk++){
    int i = li + 8*kk;
    float s1=0,s2=0;
    for(int j=0;j<HH;j++){
      float sm = ssl[i][j];
      s1 = fmaf(sm, vs[c][j], s1);
      s2 = fmaf(sm, rv[c][i-j+55], s2);
    }
    svw[base+i]=f2bf(s1); svew[base+i]=f2bf(s2);
    p0+=s1; p1+=s1*s1; p2+=s2; p3+=s2*s2;
  }
  #pragma unroll
  for(int msk=1;msk<8;msk<<=1){
    p0+=__shfl_xor(p0,msk); p1+=__shfl_xor(p1,msk);
    p2+=__shfl_xor(p2,msk); p3+=__shfl_xor(p3,msk);
  }
  if(li==0){ ost[c][0]=p0; ost[c][1]=p1; ost[c][2]=p2; ost[c][3]=p3; }
  __syncthreads();
  if(t<GPF){
    int ch0 = g*64 + 2*t;
    atomicAdd(&fws[F_OSUM+ch0],   ost[t][0]);
    atomicAdd(&fws[F_OSQ+ch0],    ost[t][1]);
    atomicAdd(&fws[F_OSUM+ch0+1], ost[t][2]);
    atomicAdd(&fws[F_OSQ+ch0+1],  ost[t][3]);
  }
}

// K8: finalize out BN
__global__ void k_finout(const float* og, const float* ob, float* fws){
  int o = threadIdx.x;
  float m = fws[F_OSUM+o]*(1.0f/CNT_PROJ);
  float var = fws[F_OSQ+o]*(1.0f/CNT_PROJ) - m*m;
  float a = og[o]*rsqrtf(var+EPSV);
  fws[F_OA+o]=a; fws[F_OB+o]=ob[o]-m*a;
}

// K9: combine + transpose to out[n][oc][h][w]
__global__ __launch_bounds__(256) void k_out(const bf16* __restrict__ svw, const bf16* __restrict__ svew,
                                             const float* __restrict__ fws, float* __restrict__ out){
  int oc = blockIdx.x, n = blockIdx.y;
  int g = oc>>5, c = oc&31;
  __shared__ float s1l[WW][57], s2l[WW][57];
  int t=threadIdx.x;
  for(int idx=t; idx<SSP; idx+=256){
    int w = idx/HH, h = idx-w*HH;
    size_t base = (((size_t)(n*WW+w)*GG+g)*GPF+c)*HH;
    s1l[w][h]=bf2f(svw[base+h]); s2l[w][h]=bf2f(svew[base+h]);
  }
  int ch0 = g*64+2*c;
  float a1=fws[F_OA+ch0], b1=fws[F_OB+ch0], a2=fws[F_OA+ch0+1], b2=fws[F_OB+ch0+1];
  __syncthreads();
  for(int idx=t; idx<SSP; idx+=256){
    int h = idx/WW, w2 = idx-h*WW;
    out[((size_t)(n*CCH+oc)*HH + h)*WW + w2] = a1*s1l[w2][h]+b1 + a2*s2l[w2][h]+b2;
  }
}

extern "C" void kernel_launch(void* const* d_in, const int* in_sizes, int n_in,
                              void* d_out, int out_size, void* d_ws, size_t ws_size,
                              hipStream_t stream) {
  const float* x    = (const float*)d_in[0];
  const float* xd   = (const float*)d_in[1];
  const float* carw = (const float*)d_in[2];
  const float* carb = (const float*)d_in[3];
  const float* cadw = (const float*)d_in[4];
  const float* cadb = (const float*)d_in[5];
  const float* qw   = (const float*)d_in[6];
  const float* kw   = (const float*)d_in[7];
  const float* vw   = (const float*)d_in[8];
  const float* bnqg = (const float*)d_in[9];
  const float* bnqb = (const float*)d_in[10];
  const float* bnkg = (const float*)d_in[11];
  const float* bnkb = (const float*)d_in[12];
  const float* bnvg = (const float*)d_in[13];
  const float* bnvb = (const float*)d_in[14];
  const float* bnsg = (const float*)d_in[15];
  const float* bnsb = (const float*)d_in[16];
  const float* bnog = (const float*)d_in[17];
  const float* bnob = (const float*)d_in[18];
  const float* rel  = (const float*)d_in[19];
  float* out = (float*)d_out;

  char* ws = (char*)d_ws;
  const size_t PROJ_BYTES = (size_t)NN*OCT*SSP*sizeof(bf16);       // 51,380,224
  const size_t SV_BYTES   = (size_t)896*GG*GPF*HH*sizeof(bf16);    // 25,690,112
  const size_t NEEDED = PROJ_BYTES + 2*SV_BYTES + (size_t)F_TOT*sizeof(float);
  if (ws_size < NEEDED) return;  // diagnostic guard: silent fail => ws too small

  bf16* proj = (bf16*)ws;
  bf16* svw  = (bf16*)(ws + PROJ_BYTES);
  bf16* svew = (bf16*)(ws + PROJ_BYTES + SV_BYTES);
  float* fws = (float*)(ws + PROJ_BYTES + 2*SV_BYTES);

  hipMemsetAsync(fws, 0, (size_t)F_TOT*sizeof(float), stream);
  k_meanpool<<<NN*CCH, 256, 0, stream>>>(x, xd, fws);
  k_chanatt<<<1, 256, 0, stream>>>(carw, carb, cadw, cadb, fws);
  k_proj<<<dim3(25,8,NN), 256, 0, stream>>>(x, xd, qw, kw, vw, fws, proj);
  k_finproj<<<1, 512, 0, stream>>>(bnqg,bnqb,bnkg,bnkb,bnvg,bnvb, fws);
  k_passA<<<dim3(GG,WW,NN), 256, 0, stream>>>(proj, rel, fws);
  k_finsim<<<1, 32, 0, stream>>>(bnsg, bnsb, fws);
  k_passB<<<dim3(GG,WW,NN), 256, 0, stream>>>(proj, rel, fws, svw, svew);
  k_finout<<<1, 512, 0, stream>>>(bnog, bnob, fws);
  k_out<<<dim3(CCH,NN), 256, 0, stream>>>(svw, svew, fws, out);
}

// Round 2
// 1098.824 us; speedup vs baseline: 1.2443x; 1.2443x over previous
//
#include <hip/hip_runtime.h>
#include <hip/hip_bf16.h>
#include <math.h>

typedef __hip_bfloat16 bf16;
typedef __attribute__((ext_vector_type(8))) short bf16x8;
typedef __attribute__((ext_vector_type(4))) float f32x4;

#define NN 16
#define CCH 256
#define HH 56
#define WW 56
#define SSP 3136
#define GG 8
#define GPH 16
#define GPF 32
#define OCT 512
#define RL 111
#define EPSV 1e-5f
#define CNT_PROJ 50176.0f
#define CNT_SIM  2809856.0f

__device__ __forceinline__ float bf2f(bf16 v){ return __bfloat162float(v); }
__device__ __forceinline__ bf16 f2bf(float v){ return __float2bfloat16(v); }
__device__ __forceinline__ short f2s(float f){ bf16 h = __float2bfloat16(f); return __builtin_bit_cast(short, h); }
__device__ __forceinline__ float s2f(short s){ bf16 h = __builtin_bit_cast(bf16, s); return __bfloat162float(h); }

// ---- f32 workspace region layout (float indices) ----
#define F_PR 0
#define F_PD 4096
#define F_SR 8192
#define F_SD 12288
#define F_PSUM 16384
#define F_PSQ  16896
#define F_PA   17408
#define F_PB   17920
#define F_SSUM 18432
#define F_SSQ  18464
#define F_SA   18496
#define F_SB   18528
#define F_OSUM 18560
#define F_OSQ  19072
#define F_OA   19584
#define F_OB   20096
#define F_TOT  20608
// bf16 table region (shorts), appended after fws
#define T_RQ 0
#define T_RK 3584
#define T_RV 7168
#define T_TOT 11264

// LDS byte offsets (non-stats kernel)
#define OFF_QA   0        // short[64][40]
#define OFF_KA   5120     // short[64][40]
#define OFF_QR   10240    // short[56][114]
#define OFF_KR   23008    // short[56][114]
#define OFF_SS   35776    // float[56][66]
#define OFF_VB   50560    // short[32][72]
#define OFF_OST  55168    // float[128]
#define SMSZ_B   55680
// aliases (phase 3+)
#define OFF_SIMA 0        // short[64][72]
#define OFF_SIMSH 9216    // short[64][136]
// stats kernel
#define OFF_STAT 35776    // float[6]
#define SMSZ_A   35808

// K1: per-(n,c) spatial means
__global__ __launch_bounds__(256) void k_meanpool(const float* __restrict__ x,
                                                  const float* __restrict__ xd,
                                                  float* __restrict__ fws){
  int nc = blockIdx.x;
  const float* px  = x  + (size_t)nc*SSP;
  const float* pxd = xd + (size_t)nc*SSP;
  float s1=0.f, s2=0.f;
  for(int i=threadIdx.x;i<SSP;i+=256){ s1+=px[i]; s2+=pxd[i]; }
  __shared__ float r1[256], r2[256];
  int t=threadIdx.x;
  r1[t]=s1; r2[t]=s2; __syncthreads();
  for(int st=128;st>0;st>>=1){ if(t<st){ r1[t]+=r1[t+st]; r2[t]+=r2[t+st]; } __syncthreads(); }
  if(t==0){ fws[F_PR+nc]=r1[0]*(1.f/SSP); fws[F_PD+nc]=r2[0]*(1.f/SSP); }
}

// K2: channel attention scales
__global__ __launch_bounds__(256) void k_chanatt(const float* __restrict__ wr, const float* __restrict__ br,
                                                 const float* __restrict__ wd, const float* __restrict__ bd,
                                                 float* __restrict__ fws){
  int c = threadIdx.x;
  __shared__ float red[256];
  __shared__ float prl[256], pdl[256];
  for(int n=0;n<NN;n++){
    prl[c]=fws[F_PR+n*CCH+c]; pdl[c]=fws[F_PD+n*CCH+c];
    __syncthreads();
    float dr=br[c], dd=bd[c];
    for(int k=0;k<CCH;k++){ dr = fmaf(prl[k], wr[c*CCH+k], dr); dd = fmaf(pdl[k], wd[c*CCH+k], dd); }
    dr = fmaxf(dr,0.f); dd = fmaxf(dd,0.f);
    float car = 1.f/(1.f+expf(-dr));
    float cad = 1.f/(1.f+expf(-dd));
    float tv = car+cad;
    red[c]=tv; __syncthreads();
    for(int st=128;st>0;st>>=1){ if(c<st) red[c]=fmaxf(red[c],red[c+st]); __syncthreads(); }
    float mx = red[0]; __syncthreads();
    float e = expf(tv-mx);
    red[c]=e; __syncthreads();
    for(int st=128;st>0;st>>=1){ if(c<st) red[c]+=red[c+st]; __syncthreads(); }
    float co = e/red[0]; __syncthreads();
    fws[F_SR+n*CCH+c] = co+car;
    fws[F_SD+n*CCH+c] = co+cad;
  }
}

// K3: projection GEMM (f32 vector) + proj BN stats
__global__ __launch_bounds__(256) void k_proj(const float* __restrict__ x, const float* __restrict__ xd,
    const float* __restrict__ qw, const float* __restrict__ kw, const float* __restrict__ vw,
    float* __restrict__ fws, bf16* __restrict__ proj){
  int n = blockIdx.z;
  int zo = blockIdx.y;
  int s0 = blockIdx.x*128;
  int o0 = zo*64;
  int variant = (zo<2)?0:((zo<4)?1:2);
  const float* Wm = (variant==0)? qw : ((variant==1)? kw : vw);
  int obase = (variant==0)?0:((variant==1)?128:256);
  __shared__ __align__(16) float xs[32][128];
  __shared__ float wt[64][33];
  int t = threadIdx.x;
  int sl = t & 31;
  int og = t >> 5;
  float acc[8][4];
  #pragma unroll
  for(int m=0;m<8;m++){
    #pragma unroll
    for(int u=0;u<4;u++) acc[m][u]=0.f;
  }
  const float* srp = fws + F_SR + n*CCH;
  const float* sdp = fws + F_SD + n*CCH;
  for(int cc=0; cc<CCH; cc+=32){
    for(int idx=t; idx<32*128; idx+=256){
      int ci = idx>>7, si = idx&127;
      int s = s0+si;
      float v=0.f;
      if(s<SSP){
        size_t gi = ((size_t)n*CCH + (cc+ci))*SSP + s;
        if(variant==0) v = x[gi]*srp[cc+ci];
        else if(variant==1) v = xd[gi]*sdp[cc+ci];
        else v = x[gi]*xd[gi];
      }
      xs[ci][si]=v;
    }
    for(int idx=t; idx<64*32; idx+=256){
      int ol = idx>>5, ci = idx&31;
      wt[ol][ci] = Wm[(size_t)(o0-obase+ol)*CCH + (cc+ci)];
    }
    __syncthreads();
    #pragma unroll 4
    for(int ci=0;ci<32;ci++){
      float4 xv = *(const float4*)(&xs[ci][sl*4]);
      #pragma unroll
      for(int m=0;m<8;m++){
        float wv = wt[og+8*m][ci];
        acc[m][0] = fmaf(wv, xv.x, acc[m][0]);
        acc[m][1] = fmaf(wv, xv.y, acc[m][1]);
        acc[m][2] = fmaf(wv, xv.z, acc[m][2]);
        acc[m][3] = fmaf(wv, xv.w, acc[m][3]);
      }
    }
    __syncthreads();
  }
  #pragma unroll
  for(int m=0;m<8;m++){
    int o = o0 + og + 8*m;
    float s1 = acc[m][0]+acc[m][1]+acc[m][2]+acc[m][3];
    float s2 = acc[m][0]*acc[m][0]+acc[m][1]*acc[m][1]+acc[m][2]*acc[m][2]+acc[m][3]*acc[m][3];
    #pragma unroll
    for(int msk=1;msk<32;msk<<=1){ s1 += __shfl_xor(s1,msk); s2 += __shfl_xor(s2,msk); }
    if(sl==0){ atomicAdd(&fws[F_PSUM+o], s1); atomicAdd(&fws[F_PSQ+o], s2); }
    #pragma unroll
    for(int u=0;u<4;u++){
      int s = s0 + sl*4 + u;
      if(s<SSP) proj[((size_t)n*OCT+o)*SSP + s] = f2bf(acc[m][u]);
    }
  }
}

// K4: finalize proj BN
__global__ void k_finproj(const float* qg,const float* qb,const float* kg,const float* kb,
                          const float* vg,const float* vb, float* fws){
  int o = threadIdx.x;
  float m = fws[F_PSUM+o]*(1.0f/CNT_PROJ);
  float var = fws[F_PSQ+o]*(1.0f/CNT_PROJ) - m*m;
  float g,b;
  if(o<128){ g=qg[o]; b=qb[o]; }
  else if(o<256){ g=kg[o-128]; b=kb[o-128]; }
  else { g=vg[o-256]; b=vb[o-256]; }
  float a = g*rsqrtf(var+EPSV);
  fws[F_PA+o]=a; fws[F_PB+o]=b-m*a;
}

// Tables: transpose relative[] into bf16 B-fragment-friendly layouts
//  rqBg[d][c] (112x32), rkBg[d][c] (112x32), rvBg[c][d] (32x128)
__global__ __launch_bounds__(256) void k_tables(const float* __restrict__ rel, short* __restrict__ tb){
  int t = threadIdx.x;
  for(int idx=t; idx<112*32; idx+=256){
    int d = idx>>5, c = idx&31;
    short vq=0, vk=0;
    if(c<16 && d<RL){ vq = f2s(rel[c*RL+d]); vk = f2s(rel[(16+c)*RL+d]); }
    tb[T_RQ+idx]=vq; tb[T_RK+idx]=vk;
  }
  for(int idx=t; idx<32*128; idx+=256){
    int c = idx>>7, d = idx&127;
    short v=0;
    if(d<RL) v = f2s(rel[(32+c)*RL+d]);
    tb[T_RV+idx]=v;
  }
}

// K5/K7 unified MFMA attention kernel.
// STATS=1: compute sim-BN statistics only. STATS=0: full softmax + sv/sve + out stats.
template<int STATS>
__global__ __launch_bounds__(512) void k_att(const bf16* __restrict__ proj,
                                             const short* __restrict__ tb,
                                             float* __restrict__ fws,
                                             bf16* __restrict__ svw, bf16* __restrict__ svew){
  constexpr int SMSZ = STATS ? SMSZ_A : SMSZ_B;
  __shared__ __align__(16) char sm[SMSZ];
  int g = blockIdx.x, w = blockIdx.y, n = blockIdx.z;
  int tid = threadIdx.x;
  int W = tid >> 6, lane = tid & 63;
  int l15 = lane & 15, l4 = lane >> 4;
  short* qA = (short*)(sm + OFF_QA);
  short* kA = (short*)(sm + OFF_KA);
  short* qrS = (short*)(sm + OFF_QR);
  short* krS = (short*)(sm + OFF_KR);
  const short* rqBg = tb + T_RQ;
  const short* rkBg = tb + T_RK;
  const short* rvBg = tb + T_RV;
  const float* PA = fws + F_PA;
  const float* PB = fws + F_PB;

  float aqk=0, aqr=0, akr=0, bsum=0;
  if constexpr (!STATS){
    aqk = fws[F_SA+g]; aqr = fws[F_SA+8+g]; akr = fws[F_SA+16+g];
    bsum = fws[F_SB+g]+fws[F_SB+8+g]+fws[F_SB+16+g];
  }

  // ---- P1: load q,k(,v) with BN affine applied, bf16 in LDS ----
  for(int idx=tid; idx<64*40; idx+=512){
    int i = idx/40, c = idx-40*i;
    short vq=0, vk=0;
    if(c<16 && i<HH){
      int oq = g*GPH+c, ok = 128+g*GPH+c;
      vq = f2s(PA[oq]*bf2f(proj[((size_t)n*OCT+oq)*SSP + i*WW + w]) + PB[oq]);
      vk = f2s(PA[ok]*bf2f(proj[((size_t)n*OCT+ok)*SSP + i*WW + w]) + PB[ok]);
    }
    qA[idx]=vq; kA[idx]=vk;
  }
  if constexpr (!STATS){
    short* vB = (short*)(sm + OFF_VB);
    for(int idx=tid; idx<32*72; idx+=512){
      int c = idx/72, j = idx-72*c;
      short v=0;
      if(j<HH){
        int ov = 256+g*GPF+c;
        v = f2s(PA[ov]*bf2f(proj[((size_t)n*OCT+ov)*SSP + j*WW + w]) + PB[ov]);
      }
      vB[idx]=v;
    }
    if(tid<128) ((float*)(sm+OFF_OST))[tid]=0.f;
  } else {
    if(tid<6) ((float*)(sm+OFF_STAT))[tid]=0.f;
  }
  __syncthreads();

  // ---- P2a: QRsk[i][d] and KRsk[j][d] via MFMA (56 tiles over 8 waves) ----
  for(int T=W; T<56; T+=8){
    int isK = (T>=28);
    int t2 = isK ? T-28 : T;
    int ti = t2/7, td = t2-7*ti;
    int i0 = ti*16, d0 = td*16;
    const short* aBase = isK ? kA : qA;
    const short* bBase = isK ? rkBg : rqBg;
    bf16x8 av = *(const bf16x8*)(aBase + (i0+l15)*40 + l4*8);
    bf16x8 bv = *(const bf16x8*)(bBase + (d0+l15)*32 + l4*8);
    f32x4 acc = {0.f,0.f,0.f,0.f};
    acc = __builtin_amdgcn_mfma_f32_16x16x32_bf16(av, bv, acc, 0,0,0);
    short* dst = isK ? krS : qrS;
    int d = d0 + l15;
    #pragma unroll
    for(int r=0;r<4;r++){
      int i = i0 + l4*4 + r;
      if(i<HH) dst[i*114 + d] = f2s(acc[r]);
    }
  }
  __syncthreads();

  // ---- P2b: QK tiles + gather skewed qr/kr ----
  float st[6] = {0,0,0,0,0,0};
  for(int T=W; T<16; T+=8){
    int ti = T>>2, tj = T&3;
    int i0 = ti*16, j0 = tj*16;
    bf16x8 av = *(const bf16x8*)(qA + (i0+l15)*40 + l4*8);
    bf16x8 bv = *(const bf16x8*)(kA + (j0+l15)*40 + l4*8);
    f32x4 acc = {0.f,0.f,0.f,0.f};
    acc = __builtin_amdgcn_mfma_f32_16x16x32_bf16(av, bv, acc, 0,0,0);
    int j = j0 + l15;
    #pragma unroll
    for(int r=0;r<4;r++){
      int i = i0 + l4*4 + r;
      if constexpr (STATS){
        if(i<HH && j<HH){
          float vqk = acc[r];
          float vqr = s2f(qrS[i*114 + (i-j+55)]);
          float vkr = s2f(krS[j*114 + (j-i+55)]);
          st[0]+=vqk; st[1]+=vqk*vqk; st[2]+=vqr; st[3]+=vqr*vqr; st[4]+=vkr; st[5]+=vkr*vkr;
        }
      } else {
        if(i<HH){
          float v;
          if(j<HH){
            float vqr = s2f(qrS[i*114 + (i-j+55)]);
            float vkr = s2f(krS[j*114 + (j-i+55)]);
            v = aqk*acc[r] + aqr*vqr + akr*vkr + bsum;
          } else v = -3.0e38f;
          ((float*)(sm+OFF_SS))[i*66 + j] = v;
        }
      }
    }
  }

  if constexpr (STATS){
    #pragma unroll
    for(int m=32;m>=1;m>>=1){
      #pragma unroll
      for(int u=0;u<6;u++) st[u] += __shfl_xor(st[u], m);
    }
    float* sa = (float*)(sm+OFF_STAT);
    if(lane==0){
      #pragma unroll
      for(int u=0;u<6;u++) atomicAdd(&sa[u], st[u]);
    }
    __syncthreads();
    if(tid<6){
      int base = (tid&1)? F_SSQ : F_SSUM;
      int grp = tid>>1;
      atomicAdd(&fws[base + grp*8 + g], sa[tid]);
    }
    return;
  } else {
    __syncthreads();
    // ---- P3: softmax rows + build simA and skewed simSh (alias over qA/kA/QR/KR) ----
    short* simA = (short*)(sm + OFF_SIMA);
    short* simSh = (short*)(sm + OFF_SIMSH);
    const float* ssP = (const float*)(sm + OFF_SS);
    for(int rr=0; rr<7; rr++){
      int i = W*7 + rr;
      float v = (lane<HH) ? ssP[i*66 + lane] : -3.0e38f;
      float m = v;
      #pragma unroll
      for(int msk=32;msk>=1;msk>>=1) m = fmaxf(m, __shfl_xor(m, msk));
      float e = (lane<HH) ? __expf(v-m) : 0.f;
      float ssum = e;
      #pragma unroll
      for(int msk=32;msk>=1;msk>>=1) ssum += __shfl_xor(ssum, msk);
      float p = e/ssum;
      simA[i*72 + lane] = f2s(p);       // lanes>=56 wrote p=0 (e=0)
      for(int d=lane; d<136; d+=64) simSh[i*136 + d] = 0;
      if(lane<HH) simSh[i*136 + (i+55-lane)] = f2s(p);
    }
    { // zero pad row 56+W of simA/simSh
      int i2 = HH + W;
      for(int d=lane; d<72; d+=64) simA[i2*72 + d] = 0;
      for(int d=lane; d<136; d+=64) simSh[i2*136 + d] = 0;
    }
    __syncthreads();

    // ---- P4/P5: SV (K=64 from simA,vB) and SVE (K=128 from simSh,rvBg) ----
    const short* vB = (const short*)(sm + OFF_VB);
    float* ostS = (float*)(sm + OFF_OST);
    float* ostQ = ostS + 64;
    for(int T=W; T<16; T+=8){
      int isE = (T>=8);
      int tt = T&7;
      int ti = tt>>1, tc = tt&1;
      int i0 = ti*16, c0 = tc*16;
      f32x4 acc = {0.f,0.f,0.f,0.f};
      if(!isE){
        #pragma unroll
        for(int ks=0; ks<2; ks++){
          int j0 = ks*32;
          bf16x8 av = *(const bf16x8*)(simA + (i0+l15)*72 + j0 + l4*8);
          bf16x8 bv = *(const bf16x8*)(vB + (c0+l15)*72 + j0 + l4*8);
          acc = __builtin_amdgcn_mfma_f32_16x16x32_bf16(av, bv, acc, 0,0,0);
        }
      } else {
        #pragma unroll
        for(int ks=0; ks<4; ks++){
          int d0 = ks*32;
          bf16x8 av = *(const bf16x8*)(simSh + (i0+l15)*136 + d0 + l4*8);
          bf16x8 bv = *(const bf16x8*)(rvBg + (c0+l15)*128 + d0 + l4*8);
          acc = __builtin_amdgcn_mfma_f32_16x16x32_bf16(av, bv, acc, 0,0,0);
        }
      }
      int c = c0 + l15;
      int ib = i0 + l4*4;
      float s1=0.f, s2=0.f;
      if(ib+3 < HH){
        size_t gb = ((((size_t)n*WW + w)*GG + g)*GPF + c)*HH;
        bf16* dst = isE ? svew : svw;
        short4 pk;
        pk.x = f2s(acc[0]); pk.y = f2s(acc[1]); pk.z = f2s(acc[2]); pk.w = f2s(acc[3]);
        *reinterpret_cast<short4*>(dst + gb + ib) = pk;
        #pragma unroll
        for(int r=0;r<4;r++){ s1 += acc[r]; s2 += acc[r]*acc[r]; }
      }
      int u = 2*c + (isE?1:0);
      atomicAdd(&ostS[u], s1);
      atomicAdd(&ostQ[u], s2);
    }
    __syncthreads();
    if(tid<64){
      atomicAdd(&fws[F_OSUM + g*64 + tid], ostS[tid]);
      atomicAdd(&fws[F_OSQ  + g*64 + tid], ostQ[tid]);
    }
  }
}

// K6: finalize sim BN
__global__ void k_finsim(const float* sg, const float* sb, float* fws){
  int ch = threadIdx.x; if(ch>=24) return;
  float m = fws[F_SSUM+ch]*(1.0f/CNT_SIM);
  float var = fws[F_SSQ+ch]*(1.0f/CNT_SIM) - m*m;
  float a = sg[ch]*rsqrtf(var+EPSV);
  fws[F_SA+ch]=a; fws[F_SB+ch]=sb[ch]-m*a;
}

// K8: finalize out BN
__global__ void k_finout(const float* og, const float* ob, float* fws){
  int o = threadIdx.x;
  float m = fws[F_OSUM+o]*(1.0f/CNT_PROJ);
  float var = fws[F_OSQ+o]*(1.0f/CNT_PROJ) - m*m;
  float a = og[o]*rsqrtf(var+EPSV);
  fws[F_OA+o]=a; fws[F_OB+o]=ob[o]-m*a;
}

// K9: combine + transpose
__global__ __launch_bounds__(256) void k_out(const bf16* __restrict__ svw, const bf16* __restrict__ svew,
                                             const float* __restrict__ fws, float* __restrict__ out){
  int oc = blockIdx.x, n = blockIdx.y;
  int g = oc>>5, c = oc&31;
  __shared__ float s1l[WW][57], s2l[WW][57];
  int t=threadIdx.x;
  for(int idx=t; idx<SSP; idx+=256){
    int w = idx/HH, h = idx-w*HH;
    size_t base = (((size_t)(n*WW+w)*GG+g)*GPF+c)*HH;
    s1l[w][h]=bf2f(svw[base+h]); s2l[w][h]=bf2f(svew[base+h]);
  }
  int ch0 = g*64+2*c;
  float a1=fws[F_OA+ch0], b1=fws[F_OB+ch0], a2=fws[F_OA+ch0+1], b2=fws[F_OB+ch0+1];
  __syncthreads();
  for(int idx=t; idx<SSP; idx+=256){
    int h = idx/WW, w2 = idx-h*WW;
    out[((size_t)(n*CCH+oc)*HH + h)*WW + w2] = a1*s1l[w2][h]+b1 + a2*s2l[w2][h]+b2;
  }
}

extern "C" void kernel_launch(void* const* d_in, const int* in_sizes, int n_in,
                              void* d_out, int out_size, void* d_ws, size_t ws_size,
                              hipStream_t stream) {
  const float* x    = (const float*)d_in[0];
  const float* xd   = (const float*)d_in[1];
  const float* carw = (const float*)d_in[2];
  const float* carb = (const float*)d_in[3];
  const float* cadw = (const float*)d_in[4];
  const float* cadb = (const float*)d_in[5];
  const float* qw   = (const float*)d_in[6];
  const float* kw   = (const float*)d_in[7];
  const float* vw   = (const float*)d_in[8];
  const float* bnqg = (const float*)d_in[9];
  const float* bnqb = (const float*)d_in[10];
  const float* bnkg = (const float*)d_in[11];
  const float* bnkb = (const float*)d_in[12];
  const float* bnvg = (const float*)d_in[13];
  const float* bnvb = (const float*)d_in[14];
  const float* bnsg = (const float*)d_in[15];
  const float* bnsb = (const float*)d_in[16];
  const float* bnog = (const float*)d_in[17];
  const float* bnob = (const float*)d_in[18];
  const float* rel  = (const float*)d_in[19];
  float* out = (float*)d_out;

  char* ws = (char*)d_ws;
  const size_t PROJ_BYTES = (size_t)NN*OCT*SSP*sizeof(bf16);
  const size_t SV_BYTES   = (size_t)896*GG*GPF*HH*sizeof(bf16);
  const size_t FWS_BYTES  = (size_t)F_TOT*sizeof(float);       // 82432 (16B-mult)
  const size_t TB_BYTES   = (size_t)T_TOT*sizeof(short);
  const size_t NEEDED = PROJ_BYTES + 2*SV_BYTES + FWS_BYTES + TB_BYTES;
  if (ws_size < NEEDED) return;

  bf16* proj = (bf16*)ws;
  bf16* svw  = (bf16*)(ws + PROJ_BYTES);
  bf16* svew = (bf16*)(ws + PROJ_BYTES + SV_BYTES);
  float* fws = (float*)(ws + PROJ_BYTES + 2*SV_BYTES);
  short* tb  = (short*)(ws + PROJ_BYTES + 2*SV_BYTES + FWS_BYTES);

  hipMemsetAsync(fws, 0, FWS_BYTES, stream);
  k_tables<<<1, 256, 0, stream>>>(rel, tb);
  k_meanpool<<<NN*CCH, 256, 0, stream>>>(x, xd, fws);
  k_chanatt<<<1, 256, 0, stream>>>(carw, carb, cadw, cadb, fws);
  k_proj<<<dim3(25,8,NN), 256, 0, stream>>>(x, xd, qw, kw, vw, fws, proj);
  k_finproj<<<1, 512, 0, stream>>>(bnqg,bnqb,bnkg,bnkb,bnvg,bnvb, fws);
  k_att<1><<<dim3(GG,WW,NN), 512, 0, stream>>>(proj, tb, fws, nullptr, nullptr);
  k_finsim<<<1, 32, 0, stream>>>(bnsg, bnsb, fws);
  k_att<0><<<dim3(GG,WW,NN), 512, 0, stream>>>(proj, tb, fws, svw, svew);
  k_finout<<<1, 512, 0, stream>>>(bnog, bnob, fws);
  k_out<<<dim3(CCH,NN), 256, 0, stream>>>(svw, svew, fws, out);
}

// Round 3
// 983.999 us; speedup vs baseline: 1.3896x; 1.1167x over previous
//
#include <hip/hip_runtime.h>
#include <hip/hip_bf16.h>
#include <math.h>

typedef __hip_bfloat16 bf16;
typedef __attribute__((ext_vector_type(8))) short bf16x8;
typedef __attribute__((ext_vector_type(4))) float f32x4;

#define NN 16
#define CCH 256
#define HH 56
#define WW 56
#define SSP 3136
#define GG 8
#define GPH 16
#define GPF 32
#define OCT 512
#define RL 111
#define EPSV 1e-5f
#define CNT_PROJ 50176.0f
#define CNT_SIM  2809856.0f

__device__ __forceinline__ float bf2f(bf16 v){ return __bfloat162float(v); }
__device__ __forceinline__ bf16 f2bf(float v){ return __float2bfloat16(v); }
__device__ __forceinline__ short f2s(float f){ bf16 h = __float2bfloat16(f); return __builtin_bit_cast(short, h); }
__device__ __forceinline__ float s2f(short s){ bf16 h = __builtin_bit_cast(bf16, s); return __bfloat162float(h); }

// async global->LDS, 16B per lane: per-lane global addr, wave-uniform LDS base (+lane*16 by HW)
__device__ __forceinline__ void gl16(const void* g, void* l){
  __builtin_amdgcn_global_load_lds((const __attribute__((address_space(1))) void*)g,
                                   (__attribute__((address_space(3))) void*)l, 16, 0, 0);
}

// ---- f32 workspace region layout (float indices) ----
#define F_PR 0
#define F_PD 4096
#define F_SR 8192
#define F_SD 12288
#define F_PSUM 16384
#define F_PSQ  16896
#define F_PA   17408
#define F_PB   17920
#define F_SSUM 18432
#define F_SSQ  18464
#define F_SA   18496
#define F_SB   18528
#define F_OSUM 18560
#define F_OSQ  19072
#define F_OA   19584
#define F_OB   20096
#define F_TOT  20608
// bf16 table region (shorts)
#define T_RQ 0
#define T_RK 3584
#define T_RV 7168
#define T_TOT 11264

// LDS byte offsets (k_att non-stats)
#define OFF_QA   0
#define OFF_KA   5120
#define OFF_QR   10240
#define OFF_KR   23008
#define OFF_SS   35776
#define OFF_VB   50560
#define OFF_OST  55168
#define SMSZ_B   55680
#define OFF_SIMA 0
#define OFF_SIMSH 9216
#define OFF_STAT 35776
#define SMSZ_A   35808

// ============ K1: prep — transpose x/xd to bf16 [n][s][c] (+xf), accumulate mean sums ============
__global__ __launch_bounds__(256) void k_prep(const float* __restrict__ x, const float* __restrict__ xd,
                                              float* __restrict__ fws,
                                              bf16* __restrict__ xT, bf16* __restrict__ xdT, bf16* __restrict__ xfT){
  __shared__ __align__(16) short tx[32*264];
  __shared__ __align__(16) short td[32*264];
  __shared__ __align__(16) short tf[32*264];
  int s0 = blockIdx.x*32, n = blockIdx.y;
  int t = threadIdx.x;
  int si = t & 31, cg = t >> 5;
  for(int cc=0; cc<CCH; cc+=8){
    int c = cc + cg;
    size_t gi = ((size_t)n*CCH + c)*SSP + s0 + si;
    float vx = x[gi], vd = xd[gi];
    tx[si*264+c] = f2s(vx);
    td[si*264+c] = f2s(vd);
    tf[si*264+c] = f2s(vx*vd);
    float r1=vx, r2=vd;
    #pragma unroll
    for(int m=1;m<32;m<<=1){ r1+=__shfl_xor(r1,m); r2+=__shfl_xor(r2,m); }
    if(si==0){ atomicAdd(&fws[F_PR+n*CCH+c], r1); atomicAdd(&fws[F_PD+n*CCH+c], r2); }
  }
  __syncthreads();
  size_t rb = ((size_t)n*SSP + s0)*CCH;
  for(int idx=t; idx<32*32; idx+=256){
    int sr2 = idx>>5, ch = idx&31;
    float4 v1 = *(const float4*)(tx + sr2*264 + ch*8);
    float4 v2 = *(const float4*)(td + sr2*264 + ch*8);
    float4 v3 = *(const float4*)(tf + sr2*264 + ch*8);
    *reinterpret_cast<float4*>(xT  + rb + sr2*256 + ch*8) = v1;
    *reinterpret_cast<float4*>(xdT + rb + sr2*256 + ch*8) = v2;
    *reinterpret_cast<float4*>(xfT + rb + sr2*256 + ch*8) = v3;
  }
}

// ============ K2: channel attention scales (reads SUMS, scales by 1/SSP) ============
__global__ __launch_bounds__(256) void k_chanatt(const float* __restrict__ wr, const float* __restrict__ br,
                                                 const float* __restrict__ wd, const float* __restrict__ bd,
                                                 float* __restrict__ fws){
  int c = threadIdx.x;
  __shared__ float red[256];
  __shared__ float prl[256], pdl[256];
  for(int n=0;n<NN;n++){
    prl[c]=fws[F_PR+n*CCH+c]*(1.f/SSP); pdl[c]=fws[F_PD+n*CCH+c]*(1.f/SSP);
    __syncthreads();
    float dr=br[c], dd=bd[c];
    for(int k=0;k<CCH;k++){ dr = fmaf(prl[k], wr[c*CCH+k], dr); dd = fmaf(pdl[k], wd[c*CCH+k], dd); }
    dr = fmaxf(dr,0.f); dd = fmaxf(dd,0.f);
    float car = 1.f/(1.f+expf(-dr));
    float cad = 1.f/(1.f+expf(-dd));
    float tv = car+cad;
    red[c]=tv; __syncthreads();
    for(int st=128;st>0;st>>=1){ if(c<st) red[c]=fmaxf(red[c],red[c+st]); __syncthreads(); }
    float mx = red[0]; __syncthreads();
    float e = expf(tv-mx);
    red[c]=e; __syncthreads();
    for(int st=128;st>0;st>>=1){ if(c<st) red[c]+=red[c+st]; __syncthreads(); }
    float co = e/red[0]; __syncthreads();
    fws[F_SR+n*CCH+c] = co+car;
    fws[F_SD+n*CCH+c] = co+cad;
  }
}

// ============ K3: weight prep (fold channel-attention scales into q/k weights) ============
__global__ __launch_bounds__(256) void k_wprep(const float* __restrict__ qw, const float* __restrict__ kw,
                                               const float* __restrict__ vw, const float* __restrict__ fws,
                                               bf16* __restrict__ wqs, bf16* __restrict__ wks, bf16* __restrict__ vwb){
  int b = blockIdx.x, t = threadIdx.x;
  if(b<16){
    const float* sr = fws + F_SR + b*CCH;
    const float* sd = fws + F_SD + b*CCH;
    for(int idx=t; idx<128*256; idx+=256){
      int c = idx & 255;
      wqs[b*32768+idx] = f2bf(qw[idx]*sr[c]);
      wks[b*32768+idx] = f2bf(kw[idx]*sd[c]);
    }
  } else {
    for(int idx=t; idx<256*256; idx+=256) vwb[idx] = f2bf(vw[idx]);
  }
}

// ============ K4: MFMA projection GEMM: proj[n][o][s] = sum_c W'[o][c]*in[n][s][c] + BN stats ============
// tiles: 64 s x 64 o, K=256 in 4 chunks of 64, double-buffered LDS, global_load_lds w/ source swizzle
__global__ __launch_bounds__(256) void k_gemm(const bf16* __restrict__ xT, const bf16* __restrict__ xdT,
                                              const bf16* __restrict__ xfT,
                                              const bf16* __restrict__ wqs, const bf16* __restrict__ wks,
                                              const bf16* __restrict__ vwb,
                                              float* __restrict__ fws, bf16* __restrict__ proj){
  __shared__ __align__(16) char sm[33280];   // A0 A1 B0 B1 (8KB each) + stats 512B
  int bid = blockIdx.x;
  int sw = (bid & 7)*784 + (bid >> 3);       // XCD-contiguous remap (6272 = 8*784)
  int o_t = sw & 7;
  int rest = sw >> 3;
  int s_t = rest % 49;
  int n   = rest / 49;
  int s0g = s_t*64;

  const bf16* Ag = (o_t<2 ? xT : (o_t<4 ? xdT : xfT)) + (size_t)n*SSP*CCH;
  const bf16* Wg;
  if(o_t<2)      Wg = wqs + (size_t)n*32768 + o_t*64*256;
  else if(o_t<4) Wg = wks + (size_t)n*32768 + (o_t-2)*64*256;
  else           Wg = vwb + (size_t)(o_t-4)*64*256;

  int tid = threadIdx.x;
  int w = tid>>6, lane = tid&63;
  int l15 = lane & 15, l4 = lane >> 4;

  float* sst = (float*)(sm + 32768);
  if(tid<128) sst[tid]=0.f;

  f32x4 acc[2][2];
  #pragma unroll
  for(int f=0;f<2;f++){ acc[f][0]=(f32x4){0,0,0,0}; acc[f][1]=(f32x4){0,0,0,0}; }

  // stage chunk kk into buffer b (A: rows=s, B: rows=o; both [64 rows][128B], src chunk-swizzled)
  auto stage = [&](int b, int kk){
    #pragma unroll
    for(int j=0;j<2;j++){
      int rowstart = w*16 + j*8;
      int row = rowstart + (lane>>3);
      int ch  = (lane&7) ^ (row&7);
      const bf16* gA = Ag + (size_t)(s0g + row)*CCH + kk*64 + ch*8;
      gl16(gA, sm + (b?8192:0) + rowstart*128);
      const bf16* gB = Wg + (size_t)row*CCH + kk*64 + ch*8;
      gl16(gB, sm + 16384 + (b?8192:0) + rowstart*128);
    }
  };

  stage(0,0);
  __syncthreads();
  int cur=0;
  int sl0 = (w&1)*32, ol0 = (w>>1)*32;
  for(int kk=0;kk<4;kk++){
    if(kk<3) stage(cur^1, kk+1);
    const short* Ab = (const short*)(sm + (cur?8192:0));
    const short* Bb = (const short*)(sm + 16384 + (cur?8192:0));
    #pragma unroll
    for(int kh=0;kh<2;kh++){
      bf16x8 a[2], b[2];
      #pragma unroll
      for(int f=0;f<2;f++){
        int sr = sl0 + f*16 + l15;
        int chv = (kh*4 + l4) ^ (sr&7);
        a[f] = *(const bf16x8*)(Ab + sr*64 + chv*8);
      }
      #pragma unroll
      for(int e=0;e<2;e++){
        int orw = ol0 + e*16 + l15;
        int chv = (kh*4 + l4) ^ (orw&7);
        b[e] = *(const bf16x8*)(Bb + orw*64 + chv*8);
      }
      #pragma unroll
      for(int f=0;f<2;f++)
        #pragma unroll
        for(int e=0;e<2;e++)
          acc[f][e] = __builtin_amdgcn_mfma_f32_16x16x32_bf16(a[f], b[e], acc[f][e], 0,0,0);
    }
    __syncthreads();
    cur ^= 1;
  }

  // per-o stats (sum, sumsq over this block's 64 s)
  #pragma unroll
  for(int e=0;e<2;e++){
    float s1=0.f, s2=0.f;
    #pragma unroll
    for(int f=0;f<2;f++)
      #pragma unroll
      for(int r=0;r<4;r++){ float v=acc[f][e][r]; s1+=v; s2+=v*v; }
    s1 += __shfl_xor(s1,16); s2 += __shfl_xor(s2,16);
    s1 += __shfl_xor(s1,32); s2 += __shfl_xor(s2,32);
    if(l4==0){
      int ol = ol0 + e*16 + l15;
      atomicAdd(&sst[ol], s1);
      atomicAdd(&sst[64+ol], s2);
    }
  }
  // stores: lane holds 4 consecutive s for one o
  #pragma unroll
  for(int f=0;f<2;f++)
    #pragma unroll
    for(int e=0;e<2;e++){
      int sbase = s0g + (w&1)*32 + f*16 + l4*4;
      int o = o_t*64 + ol0 + e*16 + l15;
      short4 pk;
      pk.x = f2s(acc[f][e][0]); pk.y = f2s(acc[f][e][1]);
      pk.z = f2s(acc[f][e][2]); pk.w = f2s(acc[f][e][3]);
      *reinterpret_cast<short4*>(proj + ((size_t)n*OCT + o)*SSP + sbase) = pk;
    }
  __syncthreads();
  if(tid<64){
    int og = o_t*64 + tid;
    atomicAdd(&fws[F_PSUM+og], sst[tid]);
    atomicAdd(&fws[F_PSQ+og],  sst[64+tid]);
  }
}

// ============ K5: finalize proj BN ============
__global__ void k_finproj(const float* qg,const float* qb,const float* kg,const float* kb,
                          const float* vg,const float* vb, float* fws){
  int o = threadIdx.x;
  float m = fws[F_PSUM+o]*(1.0f/CNT_PROJ);
  float var = fws[F_PSQ+o]*(1.0f/CNT_PROJ) - m*m;
  float g,b;
  if(o<128){ g=qg[o]; b=qb[o]; }
  else if(o<256){ g=kg[o-128]; b=kb[o-128]; }
  else { g=vg[o-256]; b=vb[o-256]; }
  float a = g*rsqrtf(var+EPSV);
  fws[F_PA+o]=a; fws[F_PB+o]=b-m*a;
}

// Tables for attention embeddings (bf16, fragment-friendly)
__global__ __launch_bounds__(256) void k_tables(const float* __restrict__ rel, short* __restrict__ tb){
  int t = threadIdx.x;
  for(int idx=t; idx<112*32; idx+=256){
    int d = idx>>5, c = idx&31;
    short vq=0, vk=0;
    if(c<16 && d<RL){ vq = f2s(rel[c*RL+d]); vk = f2s(rel[(16+c)*RL+d]); }
    tb[T_RQ+idx]=vq; tb[T_RK+idx]=vk;
  }
  for(int idx=t; idx<32*128; idx+=256){
    int c = idx>>7, d = idx&127;
    short v=0;
    if(d<RL) v = f2s(rel[(32+c)*RL+d]);
    tb[T_RV+idx]=v;
  }
}

// ============ K6/K8 unified MFMA attention ============
template<int STATS>
__global__ __launch_bounds__(512) void k_att(const bf16* __restrict__ proj,
                                             const short* __restrict__ tb,
                                             float* __restrict__ fws,
                                             bf16* __restrict__ svw, bf16* __restrict__ svew){
  constexpr int SMSZ = STATS ? SMSZ_A : SMSZ_B;
  __shared__ __align__(16) char sm[SMSZ];
  int g = blockIdx.x, w = blockIdx.y, n = blockIdx.z;
  int tid = threadIdx.x;
  int W = tid >> 6, lane = tid & 63;
  int l15 = lane & 15, l4 = lane >> 4;
  short* qA = (short*)(sm + OFF_QA);
  short* kA = (short*)(sm + OFF_KA);
  short* qrS = (short*)(sm + OFF_QR);
  short* krS = (short*)(sm + OFF_KR);
  const short* rqBg = tb + T_RQ;
  const short* rkBg = tb + T_RK;
  const short* rvBg = tb + T_RV;
  const float* PA = fws + F_PA;
  const float* PB = fws + F_PB;

  float aqk=0, aqr=0, akr=0, bsum=0;
  if constexpr (!STATS){
    aqk = fws[F_SA+g]; aqr = fws[F_SA+8+g]; akr = fws[F_SA+16+g];
    bsum = fws[F_SB+g]+fws[F_SB+8+g]+fws[F_SB+16+g];
  }

  for(int idx=tid; idx<64*40; idx+=512){
    int i = idx/40, c = idx-40*i;
    short vq=0, vk=0;
    if(c<16 && i<HH){
      int oq = g*GPH+c, ok = 128+g*GPH+c;
      vq = f2s(PA[oq]*bf2f(proj[((size_t)n*OCT+oq)*SSP + i*WW + w]) + PB[oq]);
      vk = f2s(PA[ok]*bf2f(proj[((size_t)n*OCT+ok)*SSP + i*WW + w]) + PB[ok]);
    }
    qA[idx]=vq; kA[idx]=vk;
  }
  if constexpr (!STATS){
    short* vB = (short*)(sm + OFF_VB);
    for(int idx=tid; idx<32*72; idx+=512){
      int c = idx/72, j = idx-72*c;
      short v=0;
      if(j<HH){
        int ov = 256+g*GPF+c;
        v = f2s(PA[ov]*bf2f(proj[((size_t)n*OCT+ov)*SSP + j*WW + w]) + PB[ov]);
      }
      vB[idx]=v;
    }
    if(tid<128) ((float*)(sm+OFF_OST))[tid]=0.f;
  } else {
    if(tid<6) ((float*)(sm+OFF_STAT))[tid]=0.f;
  }
  __syncthreads();

  for(int T=W; T<56; T+=8){
    int isK = (T>=28);
    int t2 = isK ? T-28 : T;
    int ti = t2/7, td = t2-7*ti;
    int i0 = ti*16, d0 = td*16;
    const short* aBase = isK ? kA : qA;
    const short* bBase = isK ? rkBg : rqBg;
    bf16x8 av = *(const bf16x8*)(aBase + (i0+l15)*40 + l4*8);
    bf16x8 bv = *(const bf16x8*)(bBase + (d0+l15)*32 + l4*8);
    f32x4 acc = {0.f,0.f,0.f,0.f};
    acc = __builtin_amdgcn_mfma_f32_16x16x32_bf16(av, bv, acc, 0,0,0);
    short* dst = isK ? krS : qrS;
    int d = d0 + l15;
    #pragma unroll
    for(int r=0;r<4;r++){
      int i = i0 + l4*4 + r;
      if(i<HH) dst[i*114 + d] = f2s(acc[r]);
    }
  }
  __syncthreads();

  float st[6] = {0,0,0,0,0,0};
  for(int T=W; T<16; T+=8){
    int ti = T>>2, tj = T&3;
    int i0 = ti*16, j0 = tj*16;
    bf16x8 av = *(const bf16x8*)(qA + (i0+l15)*40 + l4*8);
    bf16x8 bv = *(const bf16x8*)(kA + (j0+l15)*40 + l4*8);
    f32x4 acc = {0.f,0.f,0.f,0.f};
    acc = __builtin_amdgcn_mfma_f32_16x16x32_bf16(av, bv, acc, 0,0,0);
    int j = j0 + l15;
    #pragma unroll
    for(int r=0;r<4;r++){
      int i = i0 + l4*4 + r;
      if constexpr (STATS){
        if(i<HH && j<HH){
          float vqk = acc[r];
          float vqr = s2f(qrS[i*114 + (i-j+55)]);
          float vkr = s2f(krS[j*114 + (j-i+55)]);
          st[0]+=vqk; st[1]+=vqk*vqk; st[2]+=vqr; st[3]+=vqr*vqr; st[4]+=vkr; st[5]+=vkr*vkr;
        }
      } else {
        if(i<HH){
          float v;
          if(j<HH){
            float vqr = s2f(qrS[i*114 + (i-j+55)]);
            float vkr = s2f(krS[j*114 + (j-i+55)]);
            v = aqk*acc[r] + aqr*vqr + akr*vkr + bsum;
          } else v = -3.0e38f;
          ((float*)(sm+OFF_SS))[i*66 + j] = v;
        }
      }
    }
  }

  if constexpr (STATS){
    #pragma unroll
    for(int m=32;m>=1;m>>=1){
      #pragma unroll
      for(int u=0;u<6;u++) st[u] += __shfl_xor(st[u], m);
    }
    float* sa = (float*)(sm+OFF_STAT);
    if(lane==0){
      #pragma unroll
      for(int u=0;u<6;u++) atomicAdd(&sa[u], st[u]);
    }
    __syncthreads();
    if(tid<6){
      int base = (tid&1)? F_SSQ : F_SSUM;
      int grp = tid>>1;
      atomicAdd(&fws[base + grp*8 + g], sa[tid]);
    }
    return;
  } else {
    __syncthreads();
    short* simA = (short*)(sm + OFF_SIMA);
    short* simSh = (short*)(sm + OFF_SIMSH);
    const float* ssP = (const float*)(sm + OFF_SS);
    for(int rr=0; rr<7; rr++){
      int i = W*7 + rr;
      float v = (lane<HH) ? ssP[i*66 + lane] : -3.0e38f;
      float m = v;
      #pragma unroll
      for(int msk=32;msk>=1;msk>>=1) m = fmaxf(m, __shfl_xor(m, msk));
      float e = (lane<HH) ? __expf(v-m) : 0.f;
      float ssum = e;
      #pragma unroll
      for(int msk=32;msk>=1;msk>>=1) ssum += __shfl_xor(ssum, msk);
      float p = e/ssum;
      simA[i*72 + lane] = f2s(p);
      for(int d=lane; d<136; d+=64) simSh[i*136 + d] = 0;
      if(lane<HH) simSh[i*136 + (i+55-lane)] = f2s(p);
    }
    {
      int i2 = HH + W;
      for(int d=lane; d<72; d+=64) simA[i2*72 + d] = 0;
      for(int d=lane; d<136; d+=64) simSh[i2*136 + d] = 0;
    }
    __syncthreads();

    const short* vB = (const short*)(sm + OFF_VB);
    float* ostS = (float*)(sm + OFF_OST);
    float* ostQ = ostS + 64;
    for(int T=W; T<16; T+=8){
      int isE = (T>=8);
      int tt = T&7;
      int ti = tt>>1, tc = tt&1;
      int i0 = ti*16, c0 = tc*16;
      f32x4 acc = {0.f,0.f,0.f,0.f};
      if(!isE){
        #pragma unroll
        for(int ks=0; ks<2; ks++){
          int j0 = ks*32;
          bf16x8 av = *(const bf16x8*)(simA + (i0+l15)*72 + j0 + l4*8);
          bf16x8 bv = *(const bf16x8*)(vB + (c0+l15)*72 + j0 + l4*8);
          acc = __builtin_amdgcn_mfma_f32_16x16x32_bf16(av, bv, acc, 0,0,0);
        }
      } else {
        #pragma unroll
        for(int ks=0; ks<4; ks++){
          int d0 = ks*32;
          bf16x8 av = *(const bf16x8*)(simSh + (i0+l15)*136 + d0 + l4*8);
          bf16x8 bv = *(const bf16x8*)(rvBg + (c0+l15)*128 + d0 + l4*8);
          acc = __builtin_amdgcn_mfma_f32_16x16x32_bf16(av, bv, acc, 0,0,0);
        }
      }
      int c = c0 + l15;
      int ib = i0 + l4*4;
      float s1=0.f, s2=0.f;
      if(ib+3 < HH){
        size_t gb = ((((size_t)n*WW + w)*GG + g)*GPF + c)*HH;
        bf16* dst = isE ? svew : svw;
        short4 pk;
        pk.x = f2s(acc[0]); pk.y = f2s(acc[1]); pk.z = f2s(acc[2]); pk.w = f2s(acc[3]);
        *reinterpret_cast<short4*>(dst + gb + ib) = pk;
        #pragma unroll
        for(int r=0;r<4;r++){ s1 += acc[r]; s2 += acc[r]*acc[r]; }
      }
      int u = 2*c + (isE?1:0);
      atomicAdd(&ostS[u], s1);
      atomicAdd(&ostQ[u], s2);
    }
    __syncthreads();
    if(tid<64){
      atomicAdd(&fws[F_OSUM + g*64 + tid], ostS[tid]);
      atomicAdd(&fws[F_OSQ  + g*64 + tid], ostQ[tid]);
    }
  }
}

__global__ void k_finsim(const float* sg, const float* sb, float* fws){
  int ch = threadIdx.x; if(ch>=24) return;
  float m = fws[F_SSUM+ch]*(1.0f/CNT_SIM);
  float var = fws[F_SSQ+ch]*(1.0f/CNT_SIM) - m*m;
  float a = sg[ch]*rsqrtf(var+EPSV);
  fws[F_SA+ch]=a; fws[F_SB+ch]=sb[ch]-m*a;
}

__global__ void k_finout(const float* og, const float* ob, float* fws){
  int o = threadIdx.x;
  float m = fws[F_OSUM+o]*(1.0f/CNT_PROJ);
  float var = fws[F_OSQ+o]*(1.0f/CNT_PROJ) - m*m;
  float a = og[o]*rsqrtf(var+EPSV);
  fws[F_OA+o]=a; fws[F_OB+o]=ob[o]-m*a;
}

__global__ __launch_bounds__(256) void k_out(const bf16* __restrict__ svw, const bf16* __restrict__ svew,
                                             const float* __restrict__ fws, float* __restrict__ out){
  int oc = blockIdx.x, n = blockIdx.y;
  int g = oc>>5, c = oc&31;
  __shared__ float s1l[WW][57], s2l[WW][57];
  int t=threadIdx.x;
  for(int idx=t; idx<SSP; idx+=256){
    int w = idx/HH, h = idx-w*HH;
    size_t base = (((size_t)(n*WW+w)*GG+g)*GPF+c)*HH;
    s1l[w][h]=bf2f(svw[base+h]); s2l[w][h]=bf2f(svew[base+h]);
  }
  int ch0 = g*64+2*c;
  float a1=fws[F_OA+ch0], b1=fws[F_OB+ch0], a2=fws[F_OA+ch0+1], b2=fws[F_OB+ch0+1];
  __syncthreads();
  for(int idx=t; idx<SSP; idx+=256){
    int h = idx/WW, w2 = idx-h*WW;
    out[((size_t)(n*CCH+oc)*HH + h)*WW + w2] = a1*s1l[w2][h]+b1 + a2*s2l[w2][h]+b2;
  }
}

extern "C" void kernel_launch(void* const* d_in, const int* in_sizes, int n_in,
                              void* d_out, int out_size, void* d_ws, size_t ws_size,
                              hipStream_t stream) {
  const float* x    = (const float*)d_in[0];
  const float* xd   = (const float*)d_in[1];
  const float* carw = (const float*)d_in[2];
  const float* carb = (const float*)d_in[3];
  const float* cadw = (const float*)d_in[4];
  const float* cadb = (const float*)d_in[5];
  const float* qw   = (const float*)d_in[6];
  const float* kw   = (const float*)d_in[7];
  const float* vw   = (const float*)d_in[8];
  const float* bnqg = (const float*)d_in[9];
  const float* bnqb = (const float*)d_in[10];
  const float* bnkg = (const float*)d_in[11];
  const float* bnkb = (const float*)d_in[12];
  const float* bnvg = (const float*)d_in[13];
  const float* bnvb = (const float*)d_in[14];
  const float* bnsg = (const float*)d_in[15];
  const float* bnsb = (const float*)d_in[16];
  const float* bnog = (const float*)d_in[17];
  const float* bnob = (const float*)d_in[18];
  const float* rel  = (const float*)d_in[19];
  float* out = (float*)d_out;

  char* ws = (char*)d_ws;
  const size_t PROJ_BYTES = (size_t)NN*OCT*SSP*sizeof(bf16);      // 51,380,224
  const size_t XT_BYTES   = (size_t)NN*SSP*CCH*sizeof(bf16);      // 25,690,112
  const size_t WQS_BYTES  = (size_t)NN*128*256*sizeof(bf16);      // 1,048,576
  const size_t VWB_BYTES  = (size_t)256*256*sizeof(bf16);
  const size_t FWS_BYTES  = (size_t)F_TOT*sizeof(float);
  const size_t TB_BYTES   = (size_t)T_TOT*sizeof(short);

  size_t off = 0;
  bf16* proj = (bf16*)(ws + off); off += PROJ_BYTES;
  bf16* xT   = (bf16*)(ws + off); size_t off_xT = off; off += XT_BYTES;
  bf16* xdT  = (bf16*)(ws + off); size_t off_xdT = off; off += XT_BYTES;
  bf16* xfT  = (bf16*)(ws + off); off += XT_BYTES;
  bf16* wqs  = (bf16*)(ws + off); off += WQS_BYTES;
  bf16* wks  = (bf16*)(ws + off); off += WQS_BYTES;
  bf16* vwb  = (bf16*)(ws + off); off += VWB_BYTES;
  float* fws = (float*)(ws + off); off += FWS_BYTES;
  short* tb  = (short*)(ws + off); off += TB_BYTES;
  if (ws_size < off) return;
  // svw/svew alias the xT/xdT region (dead after k_gemm)
  bf16* svw  = (bf16*)(ws + off_xT);
  bf16* svew = (bf16*)(ws + off_xdT);

  hipMemsetAsync(fws, 0, FWS_BYTES, stream);
  k_prep<<<dim3(98,NN), 256, 0, stream>>>(x, xd, fws, xT, xdT, xfT);
  k_chanatt<<<1, 256, 0, stream>>>(carw, carb, cadw, cadb, fws);
  k_wprep<<<17, 256, 0, stream>>>(qw, kw, vw, fws, wqs, wks, vwb);
  k_tables<<<1, 256, 0, stream>>>(rel, tb);
  k_gemm<<<dim3(6272), 256, 0, stream>>>(xT, xdT, xfT, wqs, wks, vwb, fws, proj);
  k_finproj<<<1, 512, 0, stream>>>(bnqg,bnqb,bnkg,bnkb,bnvg,bnvb, fws);
  k_att<1><<<dim3(GG,WW,NN), 512, 0, stream>>>(proj, tb, fws, nullptr, nullptr);
  k_finsim<<<1, 32, 0, stream>>>(bnsg, bnsb, fws);
  k_att<0><<<dim3(GG,WW,NN), 512, 0, stream>>>(proj, tb, fws, svw, svew);
  k_finout<<<1, 512, 0, stream>>>(bnog, bnob, fws);
  k_out<<<dim3(CCH,NN), 256, 0, stream>>>(svw, svew, fws, out);
}

// Round 4
// 689.559 us; speedup vs baseline: 1.9829x; 1.4270x over previous
//
#include <hip/hip_runtime.h>
#include <hip/hip_bf16.h>
#include <math.h>

typedef __hip_bfloat16 bf16;
typedef __attribute__((ext_vector_type(8))) short bf16x8;
typedef __attribute__((ext_vector_type(4))) float f32x4;

#define NN 16
#define CCH 256
#define HH 56
#define WW 56
#define SSP 3136
#define GG 8
#define GPH 16
#define GPF 32
#define OCT 512
#define RL 111
#define EPSV 1e-5f
#define CNT_PROJ 50176.0f
#define CNT_SIM  2809856.0f

__device__ __forceinline__ float bf2f(bf16 v){ return __bfloat162float(v); }
__device__ __forceinline__ bf16 f2bf(float v){ return __float2bfloat16(v); }
__device__ __forceinline__ short f2s(float f){ bf16 h = __float2bfloat16(f); return __builtin_bit_cast(short, h); }
__device__ __forceinline__ float s2f(short s){ bf16 h = __builtin_bit_cast(bf16, s); return __bfloat162float(h); }

__device__ __forceinline__ void gl16(const void* g, void* l){
  __builtin_amdgcn_global_load_lds((const __attribute__((address_space(1))) void*)g,
                                   (__attribute__((address_space(3))) void*)l, 16, 0, 0);
}

// ---- f32 workspace region layout (float indices) ----
#define F_PR 0
#define F_PD 4096
#define F_SR 8192
#define F_SD 12288
#define F_PSUM 16384
#define F_PSQ  16896
#define F_PA   17408
#define F_PB   17920
#define F_SSUM 18432
#define F_SSQ  18464
#define F_SA   18496
#define F_SB   18528
#define F_OSUM 18560
#define F_OSQ  19072
#define F_OA   19584
#define F_OB   20096
#define F_ACC_END 20608           // memset range (accumulators only)
#define F_R1Q  20608              // [16][56]
#define F_R1K  21504
#define F_R2Q  22400              // [16][16][56]
#define F_R2K  36736
#define F_TOT  51072
// bf16 table region (shorts)
#define T_RQ 0
#define T_RK 3584
#define T_RV 7168
#define T_TOT 11264

// LDS byte offsets (k_att)
#define OFF_QA   0        // short[64][40]  rows=i, cols=c (0..15 data, 16..31 zero)
#define OFF_KA   5120
#define OFF_QR   10240    // short[56][114]
#define OFF_KR   23008
#define OFF_SS   35776    // float[56][57]
#define OFF_VB   48544    // short[32][72]  rows=c, cols=j (56..63 zero)
#define OFF_OST  53152    // float[128]
#define SMSZ     53664
// aliases (phase 3+), overlay qA/kA/QR/KR (dead by then)
#define OFF_SIMA 0        // short[64][72]
#define OFF_SIMSH 9216    // short[64][136] -> ends 26624 < OFF_SS

// ============ K1: prep — transpose x/xd to bf16 [n][s'=w*56+h][c] (+xf), accumulate mean sums ============
__global__ __launch_bounds__(256) void k_prep(const float* __restrict__ x, const float* __restrict__ xd,
                                              float* __restrict__ fws,
                                              bf16* __restrict__ xT, bf16* __restrict__ xdT, bf16* __restrict__ xfT){
  __shared__ __align__(16) short tx[32*264];
  __shared__ __align__(16) short td[32*264];
  __shared__ __align__(16) short tf[32*264];
  int s0 = blockIdx.x*32, n = blockIdx.y;
  int t = threadIdx.x;
  int si = t & 31, cg = t >> 5;
  for(int cc=0; cc<CCH; cc+=8){
    int c = cc + cg;
    size_t gi = ((size_t)n*CCH + c)*SSP + s0 + si;
    float vx = x[gi], vd = xd[gi];
    tx[si*264+c] = f2s(vx);
    td[si*264+c] = f2s(vd);
    tf[si*264+c] = f2s(vx*vd);
    float r1=vx, r2=vd;
    #pragma unroll
    for(int m=1;m<32;m<<=1){ r1+=__shfl_xor(r1,m); r2+=__shfl_xor(r2,m); }
    if(si==0){ atomicAdd(&fws[F_PR+n*CCH+c], r1); atomicAdd(&fws[F_PD+n*CCH+c], r2); }
  }
  __syncthreads();
  size_t rbase = (size_t)n*SSP;
  for(int idx=t; idx<32*32; idx+=256){
    int sr2 = idx>>5, ch = idx&31;
    int sp = s0 + sr2;
    int s2 = (sp%WW)*HH + sp/WW;        // transposed spatial index
    float4 v1 = *(const float4*)(tx + sr2*264 + ch*8);
    float4 v2 = *(const float4*)(td + sr2*264 + ch*8);
    float4 v3 = *(const float4*)(tf + sr2*264 + ch*8);
    *reinterpret_cast<float4*>(xT  + (rbase + s2)*CCH + ch*8) = v1;
    *reinterpret_cast<float4*>(xdT + (rbase + s2)*CCH + ch*8) = v2;
    *reinterpret_cast<float4*>(xfT + (rbase + s2)*CCH + ch*8) = v3;
  }
}

// ============ K2: channel attention scales (one block per n) ============
__global__ __launch_bounds__(256) void k_chanatt(const float* __restrict__ wr, const float* __restrict__ br,
                                                 const float* __restrict__ wd, const float* __restrict__ bd,
                                                 float* __restrict__ fws){
  int c = threadIdx.x, n = blockIdx.x;
  __shared__ float red[256];
  __shared__ float prl[256], pdl[256];
  prl[c]=fws[F_PR+n*CCH+c]*(1.f/SSP); pdl[c]=fws[F_PD+n*CCH+c]*(1.f/SSP);
  __syncthreads();
  float dr=br[c], dd=bd[c];
  for(int k=0;k<CCH;k++){ dr = fmaf(prl[k], wr[c*CCH+k], dr); dd = fmaf(pdl[k], wd[c*CCH+k], dd); }
  dr = fmaxf(dr,0.f); dd = fmaxf(dd,0.f);
  float car = 1.f/(1.f+expf(-dr));
  float cad = 1.f/(1.f+expf(-dd));
  float tv = car+cad;
  red[c]=tv; __syncthreads();
  for(int st=128;st>0;st>>=1){ if(c<st) red[c]=fmaxf(red[c],red[c+st]); __syncthreads(); }
  float mx = red[0]; __syncthreads();
  float e = expf(tv-mx);
  red[c]=e; __syncthreads();
  for(int st=128;st>0;st>>=1){ if(c<st) red[c]+=red[c+st]; __syncthreads(); }
  float co = e/red[0];
  fws[F_SR+n*CCH+c] = co+car;
  fws[F_SD+n*CCH+c] = co+cad;
}

// ============ K3: weight prep ============
__global__ __launch_bounds__(256) void k_wprep(const float* __restrict__ qw, const float* __restrict__ kw,
                                               const float* __restrict__ vw, const float* __restrict__ fws,
                                               bf16* __restrict__ wqs, bf16* __restrict__ wks, bf16* __restrict__ vwb){
  int b = blockIdx.x, t = threadIdx.x;
  if(b<16){
    const float* sr = fws + F_SR + b*CCH;
    const float* sd = fws + F_SD + b*CCH;
    for(int idx=t; idx<128*256; idx+=256){
      int c = idx & 255;
      wqs[b*32768+idx] = f2bf(qw[idx]*sr[c]);
      wks[b*32768+idx] = f2bf(kw[idx]*sd[c]);
    }
  } else {
    for(int idx=t; idx<256*256; idx+=256) vwb[idx] = f2bf(vw[idx]);
  }
}

// ============ K4: MFMA projection GEMM (rows = s' = w*56+h) ============
__global__ __launch_bounds__(256) void k_gemm(const bf16* __restrict__ xT, const bf16* __restrict__ xdT,
                                              const bf16* __restrict__ xfT,
                                              const bf16* __restrict__ wqs, const bf16* __restrict__ wks,
                                              const bf16* __restrict__ vwb,
                                              float* __restrict__ fws, bf16* __restrict__ proj){
  __shared__ __align__(16) char sm[33280];
  int bid = blockIdx.x;
  int sw = (bid & 7)*784 + (bid >> 3);
  int o_t = sw & 7;
  int rest = sw >> 3;
  int s_t = rest % 49;
  int n   = rest / 49;
  int s0g = s_t*64;

  const bf16* Ag = (o_t<2 ? xT : (o_t<4 ? xdT : xfT)) + (size_t)n*SSP*CCH;
  const bf16* Wg;
  if(o_t<2)      Wg = wqs + (size_t)n*32768 + o_t*64*256;
  else if(o_t<4) Wg = wks + (size_t)n*32768 + (o_t-2)*64*256;
  else           Wg = vwb + (size_t)(o_t-4)*64*256;

  int tid = threadIdx.x;
  int w = tid>>6, lane = tid&63;
  int l15 = lane & 15, l4 = lane >> 4;

  float* sst = (float*)(sm + 32768);
  if(tid<128) sst[tid]=0.f;

  f32x4 acc[2][2];
  #pragma unroll
  for(int f=0;f<2;f++){ acc[f][0]=(f32x4){0,0,0,0}; acc[f][1]=(f32x4){0,0,0,0}; }

  auto stage = [&](int b, int kk){
    #pragma unroll
    for(int j=0;j<2;j++){
      int rowstart = w*16 + j*8;
      int row = rowstart + (lane>>3);
      int ch  = (lane&7) ^ (row&7);
      const bf16* gA = Ag + (size_t)(s0g + row)*CCH + kk*64 + ch*8;
      gl16(gA, sm + (b?8192:0) + rowstart*128);
      const bf16* gB = Wg + (size_t)row*CCH + kk*64 + ch*8;
      gl16(gB, sm + 16384 + (b?8192:0) + rowstart*128);
    }
  };

  stage(0,0);
  __syncthreads();
  int cur=0;
  int sl0 = (w&1)*32, ol0 = (w>>1)*32;
  for(int kk=0;kk<4;kk++){
    if(kk<3) stage(cur^1, kk+1);
    const short* Ab = (const short*)(sm + (cur?8192:0));
    const short* Bb = (const short*)(sm + 16384 + (cur?8192:0));
    #pragma unroll
    for(int kh=0;kh<2;kh++){
      bf16x8 a[2], b[2];
      #pragma unroll
      for(int f=0;f<2;f++){
        int sr = sl0 + f*16 + l15;
        int chv = (kh*4 + l4) ^ (sr&7);
        a[f] = *(const bf16x8*)(Ab + sr*64 + chv*8);
      }
      #pragma unroll
      for(int e=0;e<2;e++){
        int orw = ol0 + e*16 + l15;
        int chv = (kh*4 + l4) ^ (orw&7);
        b[e] = *(const bf16x8*)(Bb + orw*64 + chv*8);
      }
      #pragma unroll
      for(int f=0;f<2;f++)
        #pragma unroll
        for(int e=0;e<2;e++)
          acc[f][e] = __builtin_amdgcn_mfma_f32_16x16x32_bf16(a[f], b[e], acc[f][e], 0,0,0);
    }
    __syncthreads();
    cur ^= 1;
  }

  #pragma unroll
  for(int e=0;e<2;e++){
    float s1=0.f, s2=0.f;
    #pragma unroll
    for(int f=0;f<2;f++)
      #pragma unroll
      for(int r=0;r<4;r++){ float v=acc[f][e][r]; s1+=v; s2+=v*v; }
    s1 += __shfl_xor(s1,16); s2 += __shfl_xor(s2,16);
    s1 += __shfl_xor(s1,32); s2 += __shfl_xor(s2,32);
    if(l4==0){
      int ol = ol0 + e*16 + l15;
      atomicAdd(&sst[ol], s1);
      atomicAdd(&sst[64+ol], s2);
    }
  }
  #pragma unroll
  for(int f=0;f<2;f++)
    #pragma unroll
    for(int e=0;e<2;e++){
      int sbase = s0g + (w&1)*32 + f*16 + l4*4;
      int o = o_t*64 + ol0 + e*16 + l15;
      short4 pk;
      pk.x = f2s(acc[f][e][0]); pk.y = f2s(acc[f][e][1]);
      pk.z = f2s(acc[f][e][2]); pk.w = f2s(acc[f][e][3]);
      *reinterpret_cast<short4*>(proj + ((size_t)n*OCT + o)*SSP + sbase) = pk;
    }
  __syncthreads();
  if(tid<64){
    int og = o_t*64 + tid;
    atomicAdd(&fws[F_PSUM+og], sst[tid]);
    atomicAdd(&fws[F_PSQ+og],  sst[64+tid]);
  }
}

// ============ K5: finalize proj BN ============
__global__ void k_finproj(const float* qg,const float* qb,const float* kg,const float* kb,
                          const float* vg,const float* vb, float* fws){
  int o = threadIdx.x;
  float m = fws[F_PSUM+o]*(1.0f/CNT_PROJ);
  float var = fws[F_PSQ+o]*(1.0f/CNT_PROJ) - m*m;
  float g,b;
  if(o<128){ g=qg[o]; b=qb[o]; }
  else if(o<256){ g=kg[o-128]; b=kb[o-128]; }
  else { g=vg[o-256]; b=vb[o-256]; }
  float a = g*rsqrtf(var+EPSV);
  fws[F_PA+o]=a; fws[F_PB+o]=b-m*a;
}

// ============ Tables: bf16 fragment tables + R1/R2 sliding-window stats tables ============
__global__ __launch_bounds__(256) void k_tables(const float* __restrict__ rel, short* __restrict__ tb,
                                                float* __restrict__ fws){
  int t = threadIdx.x;
  for(int idx=t; idx<112*32; idx+=256){
    int d = idx>>5, c = idx&31;
    short vq=0, vk=0;
    if(c<16 && d<RL){ vq = f2s(rel[c*RL+d]); vk = f2s(rel[(16+c)*RL+d]); }
    tb[T_RQ+idx]=vq; tb[T_RK+idx]=vk;
  }
  for(int idx=t; idx<32*128; idx+=256){
    int c = idx>>7, d = idx&127;
    short v=0;
    if(d<RL) v = f2s(rel[(32+c)*RL+d]);
    tb[T_RV+idx]=v;
  }
  // R1[c][i] = sum_{d=i..i+55} r[c][d]   (bf16-rounded rel, matching main pass)
  if(t<32){
    int c = t&15;
    const float* rr = rel + ((t<16)? c : 16+c)*RL;
    float* dst = fws + ((t<16)? F_R1Q : F_R1K) + c*56;
    float s=0;
    for(int d=0;d<56;d++) s += s2f(f2s(rr[d]));
    dst[0]=s;
    for(int i=1;i<56;i++){ s += s2f(f2s(rr[i+55])) - s2f(f2s(rr[i-1])); dst[i]=s; }
  }
  // R2[c][c'][i] = sum_{d=i..i+55} r[c][d]*r[c'][d]
  for(int p=t; p<512; p+=256){
    int tensor = p>>8, c=(p>>4)&15, cp=p&15;
    const float* ra = rel + ((tensor? 16+c : c))*RL;
    const float* rb = rel + ((tensor? 16+cp : cp))*RL;
    float* dst = fws + (tensor? F_R2K : F_R2Q) + (c*16+cp)*56;
    float s=0;
    for(int d=0;d<56;d++) s += s2f(f2s(ra[d]))*s2f(f2s(rb[d]));
    dst[0]=s;
    for(int i=1;i<56;i++){
      s += s2f(f2s(ra[i+55]))*s2f(f2s(rb[i+55])) - s2f(f2s(ra[i-1]))*s2f(f2s(rb[i-1]));
      dst[i]=s;
    }
  }
}

// ============ K6: analytic sim-BN statistics (replaces brute-force stats pass) ============
__global__ __launch_bounds__(256) void k_simstat(const bf16* __restrict__ proj,
                                                 float* __restrict__ fws){
  __shared__ float qs[8*16*56];
  __shared__ float ks[8*16*56];
  int w = blockIdx.x, n = blockIdx.y;
  int t = threadIdx.x;
  {
    int o = t;
    float pa = fws[F_PA+o], pb = fws[F_PB+o];
    const bf16* src = proj + ((size_t)n*OCT + o)*SSP + w*HH;
    float* dst = (o<128) ? &qs[o*56] : &ks[(o-128)*56];
    #pragma unroll
    for(int j=0;j<7;j++){
      bf16x8 vv = *(const bf16x8*)(src + j*8);
      #pragma unroll
      for(int e=0;e<8;e++){
        float fv = pa*s2f(vv[e]) + pb;
        dst[j*8+e] = s2f(f2s(fv));      // round like the main pass does
      }
    }
  }
  __syncthreads();
  int g = t>>5, u = t&31;
  const float* Q = &qs[g*16*56];
  const float* K = &ks[g*16*56];
  float a0=0,a1=0,a2=0,a3=0,a4=0,a5=0;
  if(u<16){
    float qsum=0, ksum=0;
    for(int i=0;i<56;i++){ qsum += Q[u*56+i]; ksum += K[u*56+i]; }
    a0 = qsum*ksum;            // contributes to S_qk
  }
  const float* R2Q = fws + F_R2Q;
  const float* R2K = fws + F_R2K;
  for(int p=u; p<256; p+=32){
    int c = p>>4, cp = p&15;
    const float* qc = Q + c*56; const float* qp = Q + cp*56;
    const float* kc = K + c*56; const float* kp = K + cp*56;
    const float* r2q = R2Q + p*56;
    const float* r2k = R2K + p*56;
    float gq=0, gk=0, sq=0, sk=0;
    for(int i=0;i<56;i++){
      float qq = qc[i]*qp[i];
      float kk = kc[i]*kp[i];
      gq += qq; gk += kk;
      sq = fmaf(qq, r2q[i], sq);
      sk = fmaf(kk, r2k[i], sk);
    }
    a1 += gq*gk;   // SS_qk
    a3 += sq;      // SS_qr
    a5 += sk;      // SS_kr
  }
  const float* R1Q = fws + F_R1Q;
  const float* R1K = fws + F_R1K;
  for(int e=u; e<896; e+=32){
    a2 = fmaf(Q[e], R1Q[e], a2);   // S_qr
    a4 = fmaf(K[e], R1K[e], a4);   // S_kr
  }
  #pragma unroll
  for(int m=1;m<32;m<<=1){
    a0+=__shfl_xor(a0,m); a1+=__shfl_xor(a1,m); a2+=__shfl_xor(a2,m);
    a3+=__shfl_xor(a3,m); a4+=__shfl_xor(a4,m); a5+=__shfl_xor(a5,m);
  }
  if(u==0){
    atomicAdd(&fws[F_SSUM+g],    a0); atomicAdd(&fws[F_SSQ+g],    a1);
    atomicAdd(&fws[F_SSUM+8+g],  a2); atomicAdd(&fws[F_SSQ+8+g],  a3);
    atomicAdd(&fws[F_SSUM+16+g], a4); atomicAdd(&fws[F_SSQ+16+g], a5);
  }
}

__global__ void k_finsim(const float* sg, const float* sb, float* fws){
  int ch = threadIdx.x; if(ch>=24) return;
  float m = fws[F_SSUM+ch]*(1.0f/CNT_SIM);
  float var = fws[F_SSQ+ch]*(1.0f/CNT_SIM) - m*m;
  float a = sg[ch]*rsqrtf(var+EPSV);
  fws[F_SA+ch]=a; fws[F_SB+ch]=sb[ch]-m*a;
}

// ============ K7: main MFMA attention pass ============
__global__ __launch_bounds__(512) void k_att(const bf16* __restrict__ proj,
                                             const short* __restrict__ tb,
                                             float* __restrict__ fws,
                                             bf16* __restrict__ svw, bf16* __restrict__ svew){
  __shared__ __align__(16) char sm[SMSZ];
  int g = blockIdx.x, w = blockIdx.y, n = blockIdx.z;
  int tid = threadIdx.x;
  int W = tid >> 6, lane = tid & 63;
  int l15 = lane & 15, l4 = lane >> 4;
  short* qA = (short*)(sm + OFF_QA);
  short* kA = (short*)(sm + OFF_KA);
  short* qrS = (short*)(sm + OFF_QR);
  short* krS = (short*)(sm + OFF_KR);
  const short* rqBg = tb + T_RQ;
  const short* rkBg = tb + T_RK;
  const short* rvBg = tb + T_RV;
  const float* PA = fws + F_PA;
  const float* PB = fws + F_PB;

  float aqk = fws[F_SA+g], aqr = fws[F_SA+8+g], akr = fws[F_SA+16+g];
  float bsum = fws[F_SB+g]+fws[F_SB+8+g]+fws[F_SB+16+g];

  // ---- P1: vectorized load of q,k,v rows (contiguous in i), BN affine, transpose into LDS ----
  if(tid<128) ((float*)(sm+OFF_OST))[tid]=0.f;
  const bf16x8 z8 = {};
  if(tid<448){
    int rid = tid/7, ch = tid - rid*7;
    int o, c, isV=0;
    if(rid<16){ c=rid; o = g*GPH + c; }
    else if(rid<32){ c=rid-16; o = 128 + g*GPH + c; }
    else { c=rid-32; o = 256 + g*GPF + c; isV=1; }
    float pa = PA[o], pb = PB[o];
    const bf16* src = proj + ((size_t)n*OCT + o)*SSP + w*HH + ch*8;
    bf16x8 vv = *(const bf16x8*)src;
    bf16x8 rv;
    #pragma unroll
    for(int e=0;e<8;e++) rv[e] = f2s(pa*s2f(vv[e])+pb);
    if(!isV){
      short* dst = (rid<16)? qA : kA;
      #pragma unroll
      for(int e=0;e<8;e++){
        int i = ch*8+e;
        dst[i*40 + c] = rv[e];
        dst[i*40 + c + 16] = 0;       // zero upper K-half
      }
    } else {
      short* vB = (short*)(sm + OFF_VB);
      *(bf16x8*)(vB + c*72 + ch*8) = rv;
      if(ch==0) *(bf16x8*)(vB + c*72 + 56) = z8;   // zero cols 56..63
    }
  } else {
    int z = tid-448;
    short* dst = (z<32)? qA : kA;
    int rr2 = (z>>2)&7, q4 = z&3;
    *(bf16x8*)(dst + (56+rr2)*40 + q4*8) = z8;     // zero pad rows 56..63
  }
  __syncthreads();

  // ---- P2a: QRsk[i][d], KRsk[j][d] via MFMA ----
  for(int T=W; T<56; T+=8){
    int isK = (T>=28);
    int t2 = isK ? T-28 : T;
    int ti = t2/7, td = t2-7*ti;
    int i0 = ti*16, d0 = td*16;
    const short* aBase = isK ? kA : qA;
    const short* bBase = isK ? rkBg : rqBg;
    bf16x8 av = *(const bf16x8*)(aBase + (i0+l15)*40 + l4*8);
    bf16x8 bv = *(const bf16x8*)(bBase + (d0+l15)*32 + l4*8);
    f32x4 acc = {0.f,0.f,0.f,0.f};
    acc = __builtin_amdgcn_mfma_f32_16x16x32_bf16(av, bv, acc, 0,0,0);
    short* dst = isK ? krS : qrS;
    int d = d0 + l15;
    #pragma unroll
    for(int r=0;r<4;r++){
      int i = i0 + l4*4 + r;
      if(i<HH) dst[i*114 + d] = f2s(acc[r]);
    }
  }
  __syncthreads();

  // ---- P2b: QK tiles + skew-gather qr/kr, write ss ----
  for(int T=W; T<16; T+=8){
    int ti = T>>2, tj = T&3;
    int i0 = ti*16, j0 = tj*16;
    bf16x8 av = *(const bf16x8*)(qA + (i0+l15)*40 + l4*8);
    bf16x8 bv = *(const bf16x8*)(kA + (j0+l15)*40 + l4*8);
    f32x4 acc = {0.f,0.f,0.f,0.f};
    acc = __builtin_amdgcn_mfma_f32_16x16x32_bf16(av, bv, acc, 0,0,0);
    int j = j0 + l15;
    #pragma unroll
    for(int r=0;r<4;r++){
      int i = i0 + l4*4 + r;
      if(i<HH && j<HH){
        float vqr = s2f(qrS[i*114 + (i-j+55)]);
        float vkr = s2f(krS[j*114 + (j-i+55)]);
        ((float*)(sm+OFF_SS))[i*57 + j] = aqk*acc[r] + aqr*vqr + akr*vkr + bsum;
      }
    }
  }
  __syncthreads();

  // ---- P3: softmax rows + build simA and skewed simSh (alias over qA/kA/QR/KR) ----
  short* simA = (short*)(sm + OFF_SIMA);
  short* simSh = (short*)(sm + OFF_SIMSH);
  const float* ssP = (const float*)(sm + OFF_SS);
  for(int rr=0; rr<7; rr++){
    int i = W*7 + rr;
    float v = (lane<HH) ? ssP[i*57 + lane] : -3.0e38f;
    float m = v;
    #pragma unroll
    for(int msk=32;msk>=1;msk>>=1) m = fmaxf(m, __shfl_xor(m, msk));
    float e = (lane<HH) ? __expf(v-m) : 0.f;
    float ssum = e;
    #pragma unroll
    for(int msk=32;msk>=1;msk>>=1) ssum += __shfl_xor(ssum, msk);
    float p = e/ssum;
    simA[i*72 + lane] = f2s(p);
    for(int d=lane; d<136; d+=64) simSh[i*136 + d] = 0;
    if(lane<HH) simSh[i*136 + (i+55-lane)] = f2s(p);
  }
  {
    int i2 = HH + W;
    for(int d=lane; d<72; d+=64) simA[i2*72 + d] = 0;
    for(int d=lane; d<136; d+=64) simSh[i2*136 + d] = 0;
  }
  __syncthreads();

  // ---- P4/P5: SV and SVE ----
  const short* vB = (const short*)(sm + OFF_VB);
  float* ostS = (float*)(sm + OFF_OST);
  float* ostQ = ostS + 64;
  for(int T=W; T<16; T+=8){
    int isE = (T>=8);
    int tt = T&7;
    int ti = tt>>1, tc = tt&1;
    int i0 = ti*16, c0 = tc*16;
    f32x4 acc = {0.f,0.f,0.f,0.f};
    if(!isE){
      #pragma unroll
      for(int ks=0; ks<2; ks++){
        int j0 = ks*32;
        bf16x8 av = *(const bf16x8*)(simA + (i0+l15)*72 + j0 + l4*8);
        bf16x8 bv = *(const bf16x8*)(vB + (c0+l15)*72 + j0 + l4*8);
        acc = __builtin_amdgcn_mfma_f32_16x16x32_bf16(av, bv, acc, 0,0,0);
      }
    } else {
      #pragma unroll
      for(int ks=0; ks<4; ks++){
        int d0 = ks*32;
        bf16x8 av = *(const bf16x8*)(simSh + (i0+l15)*136 + d0 + l4*8);
        bf16x8 bv = *(const bf16x8*)(rvBg + (c0+l15)*128 + d0 + l4*8);
        acc = __builtin_amdgcn_mfma_f32_16x16x32_bf16(av, bv, acc, 0,0,0);
      }
    }
    int c = c0 + l15;
    int ib = i0 + l4*4;
    float s1=0.f, s2=0.f;
    if(ib+3 < HH){
      size_t gb = ((((size_t)n*WW + w)*GG + g)*GPF + c)*HH;
      bf16* dst = isE ? svew : svw;
      short4 pk;
      pk.x = f2s(acc[0]); pk.y = f2s(acc[1]); pk.z = f2s(acc[2]); pk.w = f2s(acc[3]);
      *reinterpret_cast<short4*>(dst + gb + ib) = pk;
      #pragma unroll
      for(int r=0;r<4;r++){ s1 += acc[r]; s2 += acc[r]*acc[r]; }
    }
    int u = 2*c + (isE?1:0);
    atomicAdd(&ostS[u], s1);
    atomicAdd(&ostQ[u], s2);
  }
  __syncthreads();
  if(tid<64){
    atomicAdd(&fws[F_OSUM + g*64 + tid], ostS[tid]);
    atomicAdd(&fws[F_OSQ  + g*64 + tid], ostQ[tid]);
  }
}

__global__ void k_finout(const float* og, const float* ob, float* fws){
  int o = threadIdx.x;
  float m = fws[F_OSUM+o]*(1.0f/CNT_PROJ);
  float var = fws[F_OSQ+o]*(1.0f/CNT_PROJ) - m*m;
  float a = og[o]*rsqrtf(var+EPSV);
  fws[F_OA+o]=a; fws[F_OB+o]=ob[o]-m*a;
}

__global__ __launch_bounds__(256) void k_out(const bf16* __restrict__ svw, const bf16* __restrict__ svew,
                                             const float* __restrict__ fws, float* __restrict__ out){
  int oc = blockIdx.x, n = blockIdx.y;
  int g = oc>>5, c = oc&31;
  __shared__ float s1l[WW][57], s2l[WW][57];
  int t=threadIdx.x;
  for(int idx=t; idx<SSP; idx+=256){
    int w = idx/HH, h = idx-w*HH;
    size_t base = (((size_t)(n*WW+w)*GG+g)*GPF+c)*HH;
    s1l[w][h]=bf2f(svw[base+h]); s2l[w][h]=bf2f(svew[base+h]);
  }
  int ch0 = g*64+2*c;
  float a1=fws[F_OA+ch0], b1=fws[F_OB+ch0], a2=fws[F_OA+ch0+1], b2=fws[F_OB+ch0+1];
  __syncthreads();
  for(int idx=t; idx<SSP; idx+=256){
    int h = idx/WW, w2 = idx-h*WW;
    out[((size_t)(n*CCH+oc)*HH + h)*WW + w2] = a1*s1l[w2][h]+b1 + a2*s2l[w2][h]+b2;
  }
}

extern "C" void kernel_launch(void* const* d_in, const int* in_sizes, int n_in,
                              void* d_out, int out_size, void* d_ws, size_t ws_size,
                              hipStream_t stream) {
  const float* x    = (const float*)d_in[0];
  const float* xd   = (const float*)d_in[1];
  const float* carw = (const float*)d_in[2];
  const float* carb = (const float*)d_in[3];
  const float* cadw = (const float*)d_in[4];
  const float* cadb = (const float*)d_in[5];
  const float* qw   = (const float*)d_in[6];
  const float* kw   = (const float*)d_in[7];
  const float* vw   = (const float*)d_in[8];
  const float* bnqg = (const float*)d_in[9];
  const float* bnqb = (const float*)d_in[10];
  const float* bnkg = (const float*)d_in[11];
  const float* bnkb = (const float*)d_in[12];
  const float* bnvg = (const float*)d_in[13];
  const float* bnvb = (const float*)d_in[14];
  const float* bnsg = (const float*)d_in[15];
  const float* bnsb = (const float*)d_in[16];
  const float* bnog = (const float*)d_in[17];
  const float* bnob = (const float*)d_in[18];
  const float* rel  = (const float*)d_in[19];
  float* out = (float*)d_out;

  char* ws = (char*)d_ws;
  const size_t PROJ_BYTES = (size_t)NN*OCT*SSP*sizeof(bf16);
  const size_t XT_BYTES   = (size_t)NN*SSP*CCH*sizeof(bf16);
  const size_t WQS_BYTES  = (size_t)NN*128*256*sizeof(bf16);
  const size_t VWB_BYTES  = (size_t)256*256*sizeof(bf16);
  const size_t FWS_BYTES  = (size_t)F_TOT*sizeof(float);
  const size_t TB_BYTES   = (size_t)T_TOT*sizeof(short);

  size_t off = 0;
  bf16* proj = (bf16*)(ws + off); off += PROJ_BYTES;
  bf16* xT   = (bf16*)(ws + off); size_t off_xT = off; off += XT_BYTES;
  bf16* xdT  = (bf16*)(ws + off); size_t off_xdT = off; off += XT_BYTES;
  bf16* xfT  = (bf16*)(ws + off); off += XT_BYTES;
  bf16* wqs  = (bf16*)(ws + off); off += WQS_BYTES;
  bf16* wks  = (bf16*)(ws + off); off += WQS_BYTES;
  bf16* vwb  = (bf16*)(ws + off); off += VWB_BYTES;
  float* fws = (float*)(ws + off); off += FWS_BYTES;
  short* tb  = (short*)(ws + off); off += TB_BYTES;
  if (ws_size < off) return;
  bf16* svw  = (bf16*)(ws + off_xT);
  bf16* svew = (bf16*)(ws + off_xdT);

  hipMemsetAsync(fws, 0, (size_t)F_ACC_END*sizeof(float), stream);
  k_prep<<<dim3(98,NN), 256, 0, stream>>>(x, xd, fws, xT, xdT, xfT);
  k_chanatt<<<NN, 256, 0, stream>>>(carw, carb, cadw, cadb, fws);
  k_wprep<<<17, 256, 0, stream>>>(qw, kw, vw, fws, wqs, wks, vwb);
  k_tables<<<1, 256, 0, stream>>>(rel, tb, fws);
  k_gemm<<<dim3(6272), 256, 0, stream>>>(xT, xdT, xfT, wqs, wks, vwb, fws, proj);
  k_finproj<<<1, 512, 0, stream>>>(bnqg,bnqb,bnkg,bnkb,bnvg,bnvb, fws);
  k_simstat<<<dim3(WW,NN), 256, 0, stream>>>(proj, fws);
  k_finsim<<<1, 32, 0, stream>>>(bnsg, bnsb, fws);
  k_att<<<dim3(GG,WW,NN), 512, 0, stream>>>(proj, tb, fws, svw, svew);
  k_finout<<<1, 512, 0, stream>>>(bnog, bnob, fws);
  k_out<<<dim3(CCH,NN), 256, 0, stream>>>(svw, svew, fws, out);
}

// Round 5
// 599.502 us; speedup vs baseline: 2.2808x; 1.1502x over previous
//
#include <hip/hip_runtime.h>
#include <hip/hip_bf16.h>
#include <math.h>

typedef __hip_bfloat16 bf16;
typedef __attribute__((ext_vector_type(8))) short bf16x8;
typedef __attribute__((ext_vector_type(4))) float f32x4;

#define NN 16
#define CCH 256
#define HH 56
#define WW 56
#define SSP 3136
#define GG 8
#define GPH 16
#define GPF 32
#define OCT 512
#define RL 111
#define EPSV 1e-5f
#define CNT_PROJ 50176.0f
#define CNT_SIM  2809856.0f

__device__ __forceinline__ float bf2f(bf16 v){ return __bfloat162float(v); }
__device__ __forceinline__ bf16 f2bf(float v){ return __float2bfloat16(v); }
__device__ __forceinline__ short f2s(float f){ bf16 h = __float2bfloat16(f); return __builtin_bit_cast(short, h); }
__device__ __forceinline__ float s2f(short s){ bf16 h = __builtin_bit_cast(bf16, s); return __bfloat162float(h); }

__device__ __forceinline__ void gl16(const void* g, void* l){
  __builtin_amdgcn_global_load_lds((const __attribute__((address_space(1))) void*)g,
                                   (__attribute__((address_space(3))) void*)l, 16, 0, 0);
}

// ---- f32 workspace region layout (float indices) ----
#define F_PR 0
#define F_PD 4096
#define F_SR 8192
#define F_SD 12288
#define F_PSUM 16384
#define F_PSQ  16896
#define F_PA   17408
#define F_PB   17920
#define F_SSUM 18432
#define F_SSQ  18464
#define F_SA   18496
#define F_SB   18528
#define F_OSUM 18560
#define F_OSQ  19072
#define F_OA   19584
#define F_OB   20096
#define F_ACC_END 20608
#define F_R1Q  20608
#define F_R1K  21504
#define F_R2Q  22400
#define F_R2K  36736
#define F_TOT  51072
// bf16 table region (shorts)
#define T_RQ 0        // [112][24]
#define T_RK 2688     // [112][24]
#define T_RV 5376     // [32][128]
#define T_TOT 9472

// k_att LDS layout (bytes)
#define STQ 24        // qA/kA row stride (shorts)
#define STR 114       // qrS/krS row stride (shorts)
#define STA 72        // simA / vB row stride (shorts)
#define STSH 136      // simSh row stride (shorts)
#define OFF_QA   0        // [64][24] = 3072
#define OFF_KA   3072     // 3072
#define OFF_QR   6144     // [56][114] = 12768
#define OFF_KR   18912    // 12768 -> 31680
#define OFF_VB   31680    // [32][72] = 4608 -> 36288
#define OFF_RED  36288    // [64][4] float2 = 2048 -> 38336
#define OFF_OST  38336    // 128 f32 = 512 -> 38848
#define SMSZ     38848
// aliases (softmax phase+) within [0, 31680)
#define OFF_SIMA 0        // [64][72] = 9216
#define OFF_SIMSH 9216    // [64][136] = 17408 -> 26624
#define ZERO_I4  1664     // 26624/16

// ============ K1: prep — transpose x/xd to bf16 [n][s'=w*56+h][c] (+xf), mean sums from LDS tiles ============
__global__ __launch_bounds__(256) void k_prep(const float* __restrict__ x, const float* __restrict__ xd,
                                              float* __restrict__ fws,
                                              bf16* __restrict__ xT, bf16* __restrict__ xdT, bf16* __restrict__ xfT){
  __shared__ __align__(16) short tx[32*264];
  __shared__ __align__(16) short td[32*264];
  __shared__ __align__(16) short tf[32*264];
  int s0 = blockIdx.x*32, n = blockIdx.y;
  int t = threadIdx.x;
  int si = t & 31, cg = t >> 5;
  for(int cc=0; cc<CCH; cc+=8){
    int c = cc + cg;
    size_t gi = ((size_t)n*CCH + c)*SSP + s0 + si;
    float vx = x[gi], vd = xd[gi];
    tx[si*264+c] = f2s(vx);
    td[si*264+c] = f2s(vd);
    tf[si*264+c] = f2s(vx*vd);
  }
  __syncthreads();
  { // per-c mean sums from bf16 tiles (error ~1e-4 rel — harmless downstream)
    float s1=0.f, s2=0.f;
    for(int sr=0; sr<32; sr++){ s1 += s2f(tx[sr*264+t]); s2 += s2f(td[sr*264+t]); }
    atomicAdd(&fws[F_PR+n*CCH+t], s1);
    atomicAdd(&fws[F_PD+n*CCH+t], s2);
  }
  size_t rbase = (size_t)n*SSP;
  for(int idx=t; idx<32*32; idx+=256){
    int sr2 = idx>>5, ch = idx&31;
    int sp = s0 + sr2;
    int s2 = (sp%WW)*HH + sp/WW;
    float4 v1 = *(const float4*)(tx + sr2*264 + ch*8);
    float4 v2 = *(const float4*)(td + sr2*264 + ch*8);
    float4 v3 = *(const float4*)(tf + sr2*264 + ch*8);
    *reinterpret_cast<float4*>(xT  + (rbase + s2)*CCH + ch*8) = v1;
    *reinterpret_cast<float4*>(xdT + (rbase + s2)*CCH + ch*8) = v2;
    *reinterpret_cast<float4*>(xfT + (rbase + s2)*CCH + ch*8) = v3;
  }
}

// ============ K2: channel attention scales ============
__global__ __launch_bounds__(256) void k_chanatt(const float* __restrict__ wr, const float* __restrict__ br,
                                                 const float* __restrict__ wd, const float* __restrict__ bd,
                                                 float* __restrict__ fws){
  int c = threadIdx.x, n = blockIdx.x;
  __shared__ float red[256];
  __shared__ float prl[256], pdl[256];
  prl[c]=fws[F_PR+n*CCH+c]*(1.f/SSP); pdl[c]=fws[F_PD+n*CCH+c]*(1.f/SSP);
  __syncthreads();
  float dr=br[c], dd=bd[c];
  for(int k=0;k<CCH;k++){ dr = fmaf(prl[k], wr[c*CCH+k], dr); dd = fmaf(pdl[k], wd[c*CCH+k], dd); }
  dr = fmaxf(dr,0.f); dd = fmaxf(dd,0.f);
  float car = 1.f/(1.f+expf(-dr));
  float cad = 1.f/(1.f+expf(-dd));
  float tv = car+cad;
  red[c]=tv; __syncthreads();
  for(int st=128;st>0;st>>=1){ if(c<st) red[c]=fmaxf(red[c],red[c+st]); __syncthreads(); }
  float mx = red[0]; __syncthreads();
  float e = expf(tv-mx);
  red[c]=e; __syncthreads();
  for(int st=128;st>0;st>>=1){ if(c<st) red[c]+=red[c+st]; __syncthreads(); }
  float co = e/red[0];
  fws[F_SR+n*CCH+c] = co+car;
  fws[F_SD+n*CCH+c] = co+cad;
}

// ============ K3: weight prep ============
__global__ __launch_bounds__(256) void k_wprep(const float* __restrict__ qw, const float* __restrict__ kw,
                                               const float* __restrict__ vw, const float* __restrict__ fws,
                                               bf16* __restrict__ wqs, bf16* __restrict__ wks, bf16* __restrict__ vwb){
  int b = blockIdx.x, t = threadIdx.x;
  if(b<16){
    const float* sr = fws + F_SR + b*CCH;
    const float* sd = fws + F_SD + b*CCH;
    for(int idx=t; idx<128*256; idx+=256){
      int c = idx & 255;
      wqs[b*32768+idx] = f2bf(qw[idx]*sr[c]);
      wks[b*32768+idx] = f2bf(kw[idx]*sd[c]);
    }
  } else {
    for(int idx=t; idx<256*256; idx+=256) vwb[idx] = f2bf(vw[idx]);
  }
}

// ============ K4: MFMA projection GEMM ============
__global__ __launch_bounds__(256) void k_gemm(const bf16* __restrict__ xT, const bf16* __restrict__ xdT,
                                              const bf16* __restrict__ xfT,
                                              const bf16* __restrict__ wqs, const bf16* __restrict__ wks,
                                              const bf16* __restrict__ vwb,
                                              float* __restrict__ fws, bf16* __restrict__ proj){
  __shared__ __align__(16) char sm[33280];
  int bid = blockIdx.x;
  int sw = (bid & 7)*784 + (bid >> 3);
  int o_t = sw & 7;
  int rest = sw >> 3;
  int s_t = rest % 49;
  int n   = rest / 49;
  int s0g = s_t*64;

  const bf16* Ag = (o_t<2 ? xT : (o_t<4 ? xdT : xfT)) + (size_t)n*SSP*CCH;
  const bf16* Wg;
  if(o_t<2)      Wg = wqs + (size_t)n*32768 + o_t*64*256;
  else if(o_t<4) Wg = wks + (size_t)n*32768 + (o_t-2)*64*256;
  else           Wg = vwb + (size_t)(o_t-4)*64*256;

  int tid = threadIdx.x;
  int w = tid>>6, lane = tid&63;
  int l15 = lane & 15, l4 = lane >> 4;

  float* sst = (float*)(sm + 32768);
  if(tid<128) sst[tid]=0.f;

  f32x4 acc[2][2];
  #pragma unroll
  for(int f=0;f<2;f++){ acc[f][0]=(f32x4){0,0,0,0}; acc[f][1]=(f32x4){0,0,0,0}; }

  auto stage = [&](int b, int kk){
    #pragma unroll
    for(int j=0;j<2;j++){
      int rowstart = w*16 + j*8;
      int row = rowstart + (lane>>3);
      int ch  = (lane&7) ^ (row&7);
      const bf16* gA = Ag + (size_t)(s0g + row)*CCH + kk*64 + ch*8;
      gl16(gA, sm + (b?8192:0) + rowstart*128);
      const bf16* gB = Wg + (size_t)row*CCH + kk*64 + ch*8;
      gl16(gB, sm + 16384 + (b?8192:0) + rowstart*128);
    }
  };

  stage(0,0);
  __syncthreads();
  int cur=0;
  int sl0 = (w&1)*32, ol0 = (w>>1)*32;
  for(int kk=0;kk<4;kk++){
    if(kk<3) stage(cur^1, kk+1);
    const short* Ab = (const short*)(sm + (cur?8192:0));
    const short* Bb = (const short*)(sm + 16384 + (cur?8192:0));
    #pragma unroll
    for(int kh=0;kh<2;kh++){
      bf16x8 a[2], b[2];
      #pragma unroll
      for(int f=0;f<2;f++){
        int sr = sl0 + f*16 + l15;
        int chv = (kh*4 + l4) ^ (sr&7);
        a[f] = *(const bf16x8*)(Ab + sr*64 + chv*8);
      }
      #pragma unroll
      for(int e=0;e<2;e++){
        int orw = ol0 + e*16 + l15;
        int chv = (kh*4 + l4) ^ (orw&7);
        b[e] = *(const bf16x8*)(Bb + orw*64 + chv*8);
      }
      #pragma unroll
      for(int f=0;f<2;f++)
        #pragma unroll
        for(int e=0;e<2;e++)
          acc[f][e] = __builtin_amdgcn_mfma_f32_16x16x32_bf16(a[f], b[e], acc[f][e], 0,0,0);
    }
    __syncthreads();
    cur ^= 1;
  }

  #pragma unroll
  for(int e=0;e<2;e++){
    float s1=0.f, s2=0.f;
    #pragma unroll
    for(int f=0;f<2;f++)
      #pragma unroll
      for(int r=0;r<4;r++){ float v=acc[f][e][r]; s1+=v; s2+=v*v; }
    s1 += __shfl_xor(s1,16); s2 += __shfl_xor(s2,16);
    s1 += __shfl_xor(s1,32); s2 += __shfl_xor(s2,32);
    if(l4==0){
      int ol = ol0 + e*16 + l15;
      atomicAdd(&sst[ol], s1);
      atomicAdd(&sst[64+ol], s2);
    }
  }
  #pragma unroll
  for(int f=0;f<2;f++)
    #pragma unroll
    for(int e=0;e<2;e++){
      int sbase = s0g + (w&1)*32 + f*16 + l4*4;
      int o = o_t*64 + ol0 + e*16 + l15;
      short4 pk;
      pk.x = f2s(acc[f][e][0]); pk.y = f2s(acc[f][e][1]);
      pk.z = f2s(acc[f][e][2]); pk.w = f2s(acc[f][e][3]);
      *reinterpret_cast<short4*>(proj + ((size_t)n*OCT + o)*SSP + sbase) = pk;
    }
  __syncthreads();
  if(tid<64){
    int og = o_t*64 + tid;
    atomicAdd(&fws[F_PSUM+og], sst[tid]);
    atomicAdd(&fws[F_PSQ+og],  sst[64+tid]);
  }
}

// ============ K5: finalize proj BN ============
__global__ void k_finproj(const float* qg,const float* qb,const float* kg,const float* kb,
                          const float* vg,const float* vb, float* fws){
  int o = threadIdx.x;
  float m = fws[F_PSUM+o]*(1.0f/CNT_PROJ);
  float var = fws[F_PSQ+o]*(1.0f/CNT_PROJ) - m*m;
  float g,b;
  if(o<128){ g=qg[o]; b=qb[o]; }
  else if(o<256){ g=kg[o-128]; b=kb[o-128]; }
  else { g=vg[o-256]; b=vb[o-256]; }
  float a = g*rsqrtf(var+EPSV);
  fws[F_PA+o]=a; fws[F_PB+o]=b-m*a;
}

// ============ Tables ============
__global__ __launch_bounds__(256) void k_tables(const float* __restrict__ rel, short* __restrict__ tb,
                                                float* __restrict__ fws){
  int t = threadIdx.x;
  for(int idx=t; idx<112*24; idx+=256){
    int d = idx/24, c = idx - d*24;
    short vq=0, vk=0;
    if(c<16 && d<RL){ vq = f2s(rel[c*RL+d]); vk = f2s(rel[(16+c)*RL+d]); }
    tb[T_RQ+idx]=vq; tb[T_RK+idx]=vk;
  }
  for(int idx=t; idx<32*128; idx+=256){
    int c = idx>>7, d = idx&127;
    short v=0;
    if(d<RL) v = f2s(rel[(32+c)*RL+d]);
    tb[T_RV+idx]=v;
  }
  if(t<32){
    int c = t&15;
    const float* rr = rel + ((t<16)? c : 16+c)*RL;
    float* dst = fws + ((t<16)? F_R1Q : F_R1K) + c*56;
    float s=0;
    for(int d=0;d<56;d++) s += s2f(f2s(rr[d]));
    dst[0]=s;
    for(int i=1;i<56;i++){ s += s2f(f2s(rr[i+55])) - s2f(f2s(rr[i-1])); dst[i]=s; }
  }
  for(int p=t; p<512; p+=256){
    int tensor = p>>8, c=(p>>4)&15, cp=p&15;
    const float* ra = rel + ((tensor? 16+c : c))*RL;
    const float* rb = rel + ((tensor? 16+cp : cp))*RL;
    float* dst = fws + (tensor? F_R2K : F_R2Q) + (c*16+cp)*56;
    float s=0;
    for(int d=0;d<56;d++) s += s2f(f2s(ra[d]))*s2f(f2s(rb[d]));
    dst[0]=s;
    for(int i=1;i<56;i++){
      s += s2f(f2s(ra[i+55]))*s2f(f2s(rb[i+55])) - s2f(f2s(ra[i-1]))*s2f(f2s(rb[i-1]));
      dst[i]=s;
    }
  }
}

// ============ K6: analytic sim-BN statistics (bf16 LDS, vectorized) ============
__global__ __launch_bounds__(256) void k_simstat(const bf16* __restrict__ proj,
                                                 float* __restrict__ fws){
  __shared__ __align__(16) short qs[128*56];
  __shared__ __align__(16) short ks[128*56];
  int w = blockIdx.x, n = blockIdx.y;
  int t = threadIdx.x;
  {
    int o = t;
    float pa = fws[F_PA+o], pb = fws[F_PB+o];
    const bf16* src = proj + ((size_t)n*OCT + o)*SSP + w*HH;
    short* dst = (o<128) ? &qs[o*56] : &ks[(o-128)*56];
    #pragma unroll
    for(int j=0;j<7;j++){
      bf16x8 vv = *(const bf16x8*)(src + j*8);
      bf16x8 rv;
      #pragma unroll
      for(int e=0;e<8;e++) rv[e] = f2s(pa*s2f(vv[e]) + pb);
      *(bf16x8*)(dst + j*8) = rv;
    }
  }
  __syncthreads();
  int g = t>>5, u = t&31;
  const short* Q = &qs[g*16*56];
  const short* K = &ks[g*16*56];
  float a0=0,a1=0,a2=0,a3=0,a4=0,a5=0;
  if(u<16){
    float qsum=0, ksum=0;
    #pragma unroll
    for(int i8=0;i8<7;i8++){
      bf16x8 q8 = *(const bf16x8*)(Q + u*56 + i8*8);
      bf16x8 k8 = *(const bf16x8*)(K + u*56 + i8*8);
      #pragma unroll
      for(int e=0;e<8;e++){ qsum += s2f(q8[e]); ksum += s2f(k8[e]); }
    }
    a0 = qsum*ksum;
  }
  const float* R2Q = fws + F_R2Q;
  const float* R2K = fws + F_R2K;
  for(int p=u; p<256; p+=32){
    int c = p>>4, cp = p&15;
    const short* qc = Q + c*56; const short* qp = Q + cp*56;
    const short* kc = K + c*56; const short* kp = K + cp*56;
    const float* r2q = R2Q + p*56;
    const float* r2k = R2K + p*56;
    float gq=0, gk=0, sq=0, sk=0;
    #pragma unroll
    for(int i8=0;i8<7;i8++){
      bf16x8 qc8 = *(const bf16x8*)(qc + i8*8);
      bf16x8 qp8 = *(const bf16x8*)(qp + i8*8);
      bf16x8 kc8 = *(const bf16x8*)(kc + i8*8);
      bf16x8 kp8 = *(const bf16x8*)(kp + i8*8);
      float4 rq0 = *(const float4*)(r2q + i8*8);
      float4 rq1 = *(const float4*)(r2q + i8*8 + 4);
      float4 rk0 = *(const float4*)(r2k + i8*8);
      float4 rk1 = *(const float4*)(r2k + i8*8 + 4);
      float rqv[8] = {rq0.x,rq0.y,rq0.z,rq0.w,rq1.x,rq1.y,rq1.z,rq1.w};
      float rkv[8] = {rk0.x,rk0.y,rk0.z,rk0.w,rk1.x,rk1.y,rk1.z,rk1.w};
      #pragma unroll
      for(int e=0;e<8;e++){
        float qq = s2f(qc8[e])*s2f(qp8[e]);
        float kk = s2f(kc8[e])*s2f(kp8[e]);
        gq += qq; gk += kk;
        sq = fmaf(qq, rqv[e], sq);
        sk = fmaf(kk, rkv[e], sk);
      }
    }
    a1 += gq*gk; a3 += sq; a5 += sk;
  }
  const float* R1Q = fws + F_R1Q;
  const float* R1K = fws + F_R1K;
  for(int e=u; e<896; e+=32){
    a2 = fmaf(s2f(Q[e]), R1Q[e], a2);
    a4 = fmaf(s2f(K[e]), R1K[e], a4);
  }
  #pragma unroll
  for(int m=1;m<32;m<<=1){
    a0+=__shfl_xor(a0,m); a1+=__shfl_xor(a1,m); a2+=__shfl_xor(a2,m);
    a3+=__shfl_xor(a3,m); a4+=__shfl_xor(a4,m); a5+=__shfl_xor(a5,m);
  }
  if(u==0){
    atomicAdd(&fws[F_SSUM+g],    a0); atomicAdd(&fws[F_SSQ+g],    a1);
    atomicAdd(&fws[F_SSUM+8+g],  a2); atomicAdd(&fws[F_SSQ+8+g],  a3);
    atomicAdd(&fws[F_SSUM+16+g], a4); atomicAdd(&fws[F_SSQ+16+g], a5);
  }
}

__global__ void k_finsim(const float* sg, const float* sb, float* fws){
  int ch = threadIdx.x; if(ch>=24) return;
  float m = fws[F_SSUM+ch]*(1.0f/CNT_SIM);
  float var = fws[F_SSQ+ch]*(1.0f/CNT_SIM) - m*m;
  float a = sg[ch]*rsqrtf(var+EPSV);
  fws[F_SA+ch]=a; fws[F_SB+ch]=sb[ch]-m*a;
}

// ============ K7: main MFMA attention pass (in-register softmax, 4 blocks/CU) ============
__global__ __launch_bounds__(512) void k_att(const bf16* __restrict__ proj,
                                             const short* __restrict__ tb,
                                             float* __restrict__ fws,
                                             bf16* __restrict__ svw, bf16* __restrict__ svew){
  __shared__ __align__(16) char sm[SMSZ];
  int g = blockIdx.x, w = blockIdx.y, n = blockIdx.z;
  int tid = threadIdx.x;
  int W = tid >> 6, lane = tid & 63;
  int l15 = lane & 15, l4 = lane >> 4;
  short* qA = (short*)(sm + OFF_QA);
  short* kA = (short*)(sm + OFF_KA);
  short* qrS = (short*)(sm + OFF_QR);
  short* krS = (short*)(sm + OFF_KR);
  short* vB  = (short*)(sm + OFF_VB);
  float2* red = (float2*)(sm + OFF_RED);
  const short* rqB = tb + T_RQ;
  const short* rkB = tb + T_RK;
  const short* rvBg = tb + T_RV;
  const float* PA = fws + F_PA;
  const float* PB = fws + F_PB;
  const bf16x8 z8 = {};

  float aqk = fws[F_SA+g], aqr = fws[F_SA+8+g], akr = fws[F_SA+16+g];
  float bsum = fws[F_SB+g]+fws[F_SB+8+g]+fws[F_SB+16+g];

  // ---- P1: load q,k,v rows (vectorized), BN affine, pack into LDS ----
  if(tid<128) ((float*)(sm+OFF_OST))[tid]=0.f;
  if(tid<448){
    int rid = tid/7, ch = tid - rid*7;
    int o, c, isV=0;
    if(rid<16){ c=rid; o = g*GPH + c; }
    else if(rid<32){ c=rid-16; o = 128 + g*GPH + c; }
    else { c=rid-32; o = 256 + g*GPF + c; isV=1; }
    float pa = PA[o], pb = PB[o];
    const bf16* src = proj + ((size_t)n*OCT + o)*SSP + w*HH + ch*8;
    bf16x8 vv = *(const bf16x8*)src;
    bf16x8 rv;
    #pragma unroll
    for(int e=0;e<8;e++) rv[e] = f2s(pa*s2f(vv[e])+pb);
    if(!isV){
      short* dst = (rid<16)? qA : kA;
      #pragma unroll
      for(int e=0;e<8;e++) dst[(ch*8+e)*STQ + c] = rv[e];
    } else {
      *(bf16x8*)(vB + c*STA + ch*8) = rv;
      if(ch==0){
        *(bf16x8*)(vB + c*STA + 56) = z8;
        *(bf16x8*)(vB + c*STA + 64) = z8;
      }
    }
  } else {
    int z = tid-448;   // zero rows 56..63 of qA/kA: 8 rows x 48B = 384B each -> 24 int4 each
    if(z<48){
      short* arr = (z<24)? qA : kA;
      int zz = (z<24)? z : z-24;
      *(int4*)((char*)arr + 56*STQ*2 + zz*16) = (int4){0,0,0,0};
    }
  }
  __syncthreads();

  // ---- P2a: QRsk[i][d], KRsk[j][d] via MFMA (K=16 packed, zero-half regs) ----
  for(int T=W; T<56; T+=8){
    int isK = (T>=28);
    int t2 = isK ? T-28 : T;
    int ti = t2/7, td = t2-7*ti;
    int i0 = ti*16, d0 = td*16;
    const short* aBase = isK ? kA : qA;
    const short* bBase = isK ? rkB : rqB;
    bf16x8 av = (l4<2)? *(const bf16x8*)(aBase + (i0+l15)*STQ + l4*8) : z8;
    bf16x8 bv = (l4<2)? *(const bf16x8*)(bBase + (d0+l15)*24 + l4*8) : z8;
    f32x4 acc = {0.f,0.f,0.f,0.f};
    acc = __builtin_amdgcn_mfma_f32_16x16x32_bf16(av, bv, acc, 0,0,0);
    short* dst = isK ? krS : qrS;
    int d = d0 + l15;
    #pragma unroll
    for(int r=0;r<4;r++){
      int i = i0 + l4*4 + r;
      if(i<HH) dst[i*STR + d] = f2s(acc[r]);
    }
  }
  __syncthreads();

  // ---- P2b: QK tiles + skew-gather + in-register softmax partials ----
  unsigned epk[4];   // e=exp(v-m_tile) packed as bf16 pairs, [tt*2 + (r>>1)]
  #pragma unroll
  for(int tt=0; tt<2; tt++){
    int T = W + 8*tt;
    int ti = T>>2, tj = T&3;
    int i0 = ti*16, j0 = tj*16;
    bf16x8 av = (l4<2)? *(const bf16x8*)(qA + (i0+l15)*STQ + l4*8) : z8;
    bf16x8 bv = (l4<2)? *(const bf16x8*)(kA + (j0+l15)*STQ + l4*8) : z8;
    f32x4 acc = {0.f,0.f,0.f,0.f};
    acc = __builtin_amdgcn_mfma_f32_16x16x32_bf16(av, bv, acc, 0,0,0);
    int j = j0 + l15;
    int jv = (j < HH);
    #pragma unroll
    for(int r=0;r<4;r++){
      int i = i0 + l4*4 + r;
      float vqr = s2f(qrS[i*STR + (i-j+55)]);
      float vkr = s2f(krS[j*STR + (j-i+55)]);
      float v = aqk*acc[r] + aqr*vqr + akr*vkr + bsum;
      float vm = jv ? v : -3.0e38f;
      float m = vm;
      #pragma unroll
      for(int msk=1; msk<16; msk<<=1) m = fmaxf(m, __shfl_xor(m, msk));
      float e = jv ? __expf(v - m) : 0.f;
      float s = e;
      #pragma unroll
      for(int msk=1; msk<16; msk<<=1) s += __shfl_xor(s, msk);
      unsigned bits = (unsigned)(unsigned short)f2s(e);
      if(r&1) epk[tt*2+(r>>1)] |= (bits<<16);
      else    epk[tt*2+(r>>1)] = bits;
      if(l15==0) red[(ti*16 + l4*4 + r)*4 + tj] = make_float2(m, s);
    }
  }
  __syncthreads();

  // ---- P3a: bulk-zero sim region (aliases qA/kA/qrS/krS, now dead) ----
  for(int idx=tid; idx<ZERO_I4; idx+=512) ((int4*)sm)[idx] = (int4){0,0,0,0};
  __syncthreads();

  // ---- P3b: combine softmax + scatter sim ----
  short* simA = (short*)(sm + OFF_SIMA);
  short* simSh = (short*)(sm + OFF_SIMSH);
  #pragma unroll
  for(int tt=0; tt<2; tt++){
    int T = W + 8*tt;
    int ti = T>>2, tj = T&3;
    int j = tj*16 + l15;
    #pragma unroll
    for(int r=0;r<4;r++){
      int i = ti*16 + l4*4 + r;
      int base = (ti*16 + l4*4 + r)*4;
      float2 p0 = red[base+0], p1 = red[base+1], p2 = red[base+2], p3 = red[base+3];
      float M = fmaxf(fmaxf(p0.x,p1.x), fmaxf(p2.x,p3.x));
      float S = p0.y*__expf(p0.x-M) + p1.y*__expf(p1.x-M) + p2.y*__expf(p2.x-M) + p3.y*__expf(p3.x-M);
      float2 mo = red[base+tj];
      float e = s2f((short)((epk[tt*2+(r>>1)] >> ((r&1)*16)) & 0xFFFF));
      float p = e * __expf(mo.x - M) / S;
      if(i<HH && j<HH){
        short pv = f2s(p);
        simA[i*STA + j] = pv;
        simSh[i*STSH + (i+55-j)] = pv;
      }
    }
  }
  __syncthreads();

  // ---- P4/P5: SV and SVE ----
  float* ostS = (float*)(sm + OFF_OST);
  float* ostQ = ostS + 64;
  for(int T=W; T<16; T+=8){
    int isE = (T>=8);
    int tt = T&7;
    int ti = tt>>1, tc = tt&1;
    int i0 = ti*16, c0 = tc*16;
    f32x4 acc = {0.f,0.f,0.f,0.f};
    if(!isE){
      #pragma unroll
      for(int ks=0; ks<2; ks++){
        int j0 = ks*32;
        bf16x8 av = *(const bf16x8*)(simA + (i0+l15)*STA + j0 + l4*8);
        bf16x8 bv = *(const bf16x8*)(vB + (c0+l15)*STA + j0 + l4*8);
        acc = __builtin_amdgcn_mfma_f32_16x16x32_bf16(av, bv, acc, 0,0,0);
      }
    } else {
      #pragma unroll
      for(int ks=0; ks<4; ks++){
        int d0 = ks*32;
        bf16x8 av = *(const bf16x8*)(simSh + (i0+l15)*STSH + d0 + l4*8);
        bf16x8 bv = *(const bf16x8*)(rvBg + (c0+l15)*128 + d0 + l4*8);
        acc = __builtin_amdgcn_mfma_f32_16x16x32_bf16(av, bv, acc, 0,0,0);
      }
    }
    int c = c0 + l15;
    int ib = i0 + l4*4;
    float s1=0.f, s2=0.f;
    if(ib+3 < HH){
      size_t gb = ((((size_t)n*WW + w)*GG + g)*GPF + c)*HH;
      bf16* dst = isE ? svew : svw;
      short4 pk;
      pk.x = f2s(acc[0]); pk.y = f2s(acc[1]); pk.z = f2s(acc[2]); pk.w = f2s(acc[3]);
      *reinterpret_cast<short4*>(dst + gb + ib) = pk;
      #pragma unroll
      for(int r=0;r<4;r++){ s1 += acc[r]; s2 += acc[r]*acc[r]; }
    }
    int u = 2*c + (isE?1:0);
    atomicAdd(&ostS[u], s1);
    atomicAdd(&ostQ[u], s2);
  }
  __syncthreads();
  if(tid<64){
    atomicAdd(&fws[F_OSUM + g*64 + tid], ostS[tid]);
    atomicAdd(&fws[F_OSQ  + g*64 + tid], ostQ[tid]);
  }
}

__global__ void k_finout(const float* og, const float* ob, float* fws){
  int o = threadIdx.x;
  float m = fws[F_OSUM+o]*(1.0f/CNT_PROJ);
  float var = fws[F_OSQ+o]*(1.0f/CNT_PROJ) - m*m;
  float a = og[o]*rsqrtf(var+EPSV);
  fws[F_OA+o]=a; fws[F_OB+o]=ob[o]-m*a;
}

__global__ __launch_bounds__(256) void k_out(const bf16* __restrict__ svw, const bf16* __restrict__ svew,
                                             const float* __restrict__ fws, float* __restrict__ out){
  int oc = blockIdx.x, n = blockIdx.y;
  int g = oc>>5, c = oc&31;
  __shared__ float s1l[WW][57], s2l[WW][57];
  int t=threadIdx.x;
  for(int idx=t; idx<392; idx+=256){
    int w = idx/7, hc = idx-w*7;
    size_t base = (((size_t)(n*WW+w)*GG+g)*GPF+c)*HH + hc*8;
    bf16x8 v1 = *(const bf16x8*)(svw+base);
    bf16x8 v2 = *(const bf16x8*)(svew+base);
    #pragma unroll
    for(int e=0;e<8;e++){
      s1l[w][hc*8+e] = s2f(v1[e]);
      s2l[w][hc*8+e] = s2f(v2[e]);
    }
  }
  int ch0 = g*64+2*c;
  float a1=fws[F_OA+ch0], b1=fws[F_OB+ch0], a2=fws[F_OA+ch0+1], b2=fws[F_OB+ch0+1];
  __syncthreads();
  for(int idx=t; idx<SSP; idx+=256){
    int h = idx/WW, w2 = idx-h*WW;
    out[((size_t)(n*CCH+oc)*HH + h)*WW + w2] = a1*s1l[w2][h]+b1 + a2*s2l[w2][h]+b2;
  }
}

extern "C" void kernel_launch(void* const* d_in, const int* in_sizes, int n_in,
                              void* d_out, int out_size, void* d_ws, size_t ws_size,
                              hipStream_t stream) {
  const float* x    = (const float*)d_in[0];
  const float* xd   = (const float*)d_in[1];
  const float* carw = (const float*)d_in[2];
  const float* carb = (const float*)d_in[3];
  const float* cadw = (const float*)d_in[4];
  const float* cadb = (const float*)d_in[5];
  const float* qw   = (const float*)d_in[6];
  const float* kw   = (const float*)d_in[7];
  const float* vw   = (const float*)d_in[8];
  const float* bnqg = (const float*)d_in[9];
  const float* bnqb = (const float*)d_in[10];
  const float* bnkg = (const float*)d_in[11];
  const float* bnkb = (const float*)d_in[12];
  const float* bnvg = (const float*)d_in[13];
  const float* bnvb = (const float*)d_in[14];
  const float* bnsg = (const float*)d_in[15];
  const float* bnsb = (const float*)d_in[16];
  const float* bnog = (const float*)d_in[17];
  const float* bnob = (const float*)d_in[18];
  const float* rel  = (const float*)d_in[19];
  float* out = (float*)d_out;

  char* ws = (char*)d_ws;
  const size_t PROJ_BYTES = (size_t)NN*OCT*SSP*sizeof(bf16);
  const size_t XT_BYTES   = (size_t)NN*SSP*CCH*sizeof(bf16);
  const size_t WQS_BYTES  = (size_t)NN*128*256*sizeof(bf16);
  const size_t VWB_BYTES  = (size_t)256*256*sizeof(bf16);
  const size_t FWS_BYTES  = (size_t)F_TOT*sizeof(float);
  const size_t TB_BYTES   = (size_t)((T_TOT+7)/8*8)*sizeof(short);

  size_t off = 0;
  bf16* proj = (bf16*)(ws + off); off += PROJ_BYTES;
  bf16* xT   = (bf16*)(ws + off); size_t off_xT = off; off += XT_BYTES;
  bf16* xdT  = (bf16*)(ws + off); size_t off_xdT = off; off += XT_BYTES;
  bf16* xfT  = (bf16*)(ws + off); off += XT_BYTES;
  bf16* wqs  = (bf16*)(ws + off); off += WQS_BYTES;
  bf16* wks  = (bf16*)(ws + off); off += WQS_BYTES;
  bf16* vwb  = (bf16*)(ws + off); off += VWB_BYTES;
  float* fws = (float*)(ws + off); off += FWS_BYTES;
  short* tb  = (short*)(ws + off); off += TB_BYTES;
  if (ws_size < off) return;
  bf16* svw  = (bf16*)(ws + off_xT);
  bf16* svew = (bf16*)(ws + off_xdT);

  hipMemsetAsync(fws, 0, (size_t)F_ACC_END*sizeof(float), stream);
  k_prep<<<dim3(98,NN), 256, 0, stream>>>(x, xd, fws, xT, xdT, xfT);
  k_chanatt<<<NN, 256, 0, stream>>>(carw, carb, cadw, cadb, fws);
  k_wprep<<<17, 256, 0, stream>>>(qw, kw, vw, fws, wqs, wks, vwb);
  k_tables<<<1, 256, 0, stream>>>(rel, tb, fws);
  k_gemm<<<dim3(6272), 256, 0, stream>>>(xT, xdT, xfT, wqs, wks, vwb, fws, proj);
  k_finproj<<<1, 512, 0, stream>>>(bnqg,bnqb,bnkg,bnkb,bnvg,bnvb, fws);
  k_simstat<<<dim3(WW,NN), 256, 0, stream>>>(proj, fws);
  k_finsim<<<1, 32, 0, stream>>>(bnsg, bnsb, fws);
  k_att<<<dim3(GG,WW,NN), 512, 0, stream>>>(proj, tb, fws, svw, svew);
  k_finout<<<1, 512, 0, stream>>>(bnog, bnob, fws);
  k_out<<<dim3(CCH,NN), 256, 0, stream>>>(svw, svew, fws, out);
}

// Round 6
// 558.688 us; speedup vs baseline: 2.4474x; 1.0731x over previous
//
#include <hip/hip_runtime.h>
#include <hip/hip_bf16.h>
#include <math.h>

typedef __hip_bfloat16 bf16;
typedef __attribute__((ext_vector_type(8))) short bf16x8;
typedef __attribute__((ext_vector_type(4))) short s16x4;
typedef __attribute__((ext_vector_type(4))) float f32x4;

#define NN 16
#define CCH 256
#define HH 56
#define WW 56
#define SSP 3136
#define GG 8
#define GPH 16
#define GPF 32
#define OCT 512
#define RL 111
#define EPSV 1e-5f
#define CNT_PROJ 50176.0f
#define CNT_SIM  2809856.0f

__device__ __forceinline__ float bf2f(bf16 v){ return __bfloat162float(v); }
__device__ __forceinline__ bf16 f2bf(float v){ return __float2bfloat16(v); }
__device__ __forceinline__ short f2s(float f){ bf16 h = __float2bfloat16(f); return __builtin_bit_cast(short, h); }
__device__ __forceinline__ float s2f(short s){ bf16 h = __builtin_bit_cast(bf16, s); return __bfloat162float(h); }
__device__ __forceinline__ unsigned pk2(float a, float b){
  return (unsigned)(unsigned short)f2s(a) | ((unsigned)(unsigned short)f2s(b)<<16);
}

__device__ __forceinline__ void gl16(const void* g, void* l){
  __builtin_amdgcn_global_load_lds((const __attribute__((address_space(1))) void*)g,
                                   (__attribute__((address_space(3))) void*)l, 16, 0, 0);
}

// ---- f32 workspace region layout (float indices) ----
#define F_PR 0
#define F_PD 4096
#define F_SR 8192
#define F_SD 12288
#define F_PSUM 16384
#define F_PSQ  16896
#define F_PA   17408
#define F_PB   17920
#define F_SSUM 18432
#define F_SSQ  18464
#define F_SA   18496
#define F_SB   18528
#define F_OSUM 18560
#define F_OSQ  19072
#define F_OA   19584
#define F_OB   20096
#define F_ACC_END 20608
#define F_R1Q  20608
#define F_R1K  21504
#define F_R2Q  22400
#define F_R2K  36736
#define F_TOT  51072
// bf16 table region (shorts)
#define T_RQ 0        // [112][24]
#define T_RK 2688     // [112][24]
#define T_RV 5376     // [32][128]
#define T_TOT 9472

// k_att LDS layout (bytes)
#define STQ 24        // qA/kA row stride (shorts)
#define SQT 58        // qrT/krT row stride (shorts) — [d][i], dword-stride 29 (conflict-free)
#define STA 72        // simA / vB row stride (shorts)
#define STSH 136      // simSh row stride (shorts)
#define OFF_QA   0        // [64][24] = 3072
#define OFF_KA   3072     // -> 6144
#define OFF_QR   6144     // [112][58]*2 = 12992 -> 19136
#define OFF_KR   19136    // -> 32128
#define OFF_VB   32128    // [32][72]*2 = 4608 -> 36736
#define OFF_RED  36736    // float2[64][4] = 2048 -> 38784
#define OFF_FAC  38784    // float[224] = 896 -> 39680
#define OFF_OST  39680    // float[128] = 512 -> 40192
#define SMSZ     40192
// aliases (softmax phase+) within [0, 26624) — overlays qA/kA/qrT/krT
#define OFF_SIMA 0        // [64][72] = 9216
#define OFF_SIMSH 9216    // [64][136] = 17408 -> 26624
#define ZERO_I4  1664     // 26624/16

// ============ K1: prep ============
__global__ __launch_bounds__(256) void k_prep(const float* __restrict__ x, const float* __restrict__ xd,
                                              float* __restrict__ fws,
                                              bf16* __restrict__ xT, bf16* __restrict__ xdT, bf16* __restrict__ xfT){
  __shared__ __align__(16) short tx[32*264];
  __shared__ __align__(16) short td[32*264];
  __shared__ __align__(16) short tf[32*264];
  int s0 = blockIdx.x*32, n = blockIdx.y;
  int t = threadIdx.x;
  int si = t & 31, cg = t >> 5;
  for(int cc=0; cc<CCH; cc+=8){
    int c = cc + cg;
    size_t gi = ((size_t)n*CCH + c)*SSP + s0 + si;
    float vx = x[gi], vd = xd[gi];
    tx[si*264+c] = f2s(vx);
    td[si*264+c] = f2s(vd);
    tf[si*264+c] = f2s(vx*vd);
  }
  __syncthreads();
  {
    float s1=0.f, s2=0.f;
    for(int sr=0; sr<32; sr++){ s1 += s2f(tx[sr*264+t]); s2 += s2f(td[sr*264+t]); }
    atomicAdd(&fws[F_PR+n*CCH+t], s1);
    atomicAdd(&fws[F_PD+n*CCH+t], s2);
  }
  size_t rbase = (size_t)n*SSP;
  for(int idx=t; idx<32*32; idx+=256){
    int sr2 = idx>>5, ch = idx&31;
    int sp = s0 + sr2;
    int s2 = (sp%WW)*HH + sp/WW;
    float4 v1 = *(const float4*)(tx + sr2*264 + ch*8);
    float4 v2 = *(const float4*)(td + sr2*264 + ch*8);
    float4 v3 = *(const float4*)(tf + sr2*264 + ch*8);
    *reinterpret_cast<float4*>(xT  + (rbase + s2)*CCH + ch*8) = v1;
    *reinterpret_cast<float4*>(xdT + (rbase + s2)*CCH + ch*8) = v2;
    *reinterpret_cast<float4*>(xfT + (rbase + s2)*CCH + ch*8) = v3;
  }
}

// ============ K2: channel attention scales ============
__global__ __launch_bounds__(256) void k_chanatt(const float* __restrict__ wr, const float* __restrict__ br,
                                                 const float* __restrict__ wd, const float* __restrict__ bd,
                                                 float* __restrict__ fws){
  int c = threadIdx.x, n = blockIdx.x;
  __shared__ float red[256];
  __shared__ float prl[256], pdl[256];
  prl[c]=fws[F_PR+n*CCH+c]*(1.f/SSP); pdl[c]=fws[F_PD+n*CCH+c]*(1.f/SSP);
  __syncthreads();
  float dr=br[c], dd=bd[c];
  for(int k=0;k<CCH;k++){ dr = fmaf(prl[k], wr[c*CCH+k], dr); dd = fmaf(pdl[k], wd[c*CCH+k], dd); }
  dr = fmaxf(dr,0.f); dd = fmaxf(dd,0.f);
  float car = 1.f/(1.f+expf(-dr));
  float cad = 1.f/(1.f+expf(-dd));
  float tv = car+cad;
  red[c]=tv; __syncthreads();
  for(int st=128;st>0;st>>=1){ if(c<st) red[c]=fmaxf(red[c],red[c+st]); __syncthreads(); }
  float mx = red[0]; __syncthreads();
  float e = expf(tv-mx);
  red[c]=e; __syncthreads();
  for(int st=128;st>0;st>>=1){ if(c<st) red[c]+=red[c+st]; __syncthreads(); }
  float co = e/red[0];
  fws[F_SR+n*CCH+c] = co+car;
  fws[F_SD+n*CCH+c] = co+cad;
}

// ============ K3: weight prep ============
__global__ __launch_bounds__(256) void k_wprep(const float* __restrict__ qw, const float* __restrict__ kw,
                                               const float* __restrict__ vw, const float* __restrict__ fws,
                                               bf16* __restrict__ wqs, bf16* __restrict__ wks, bf16* __restrict__ vwb){
  int b = blockIdx.x, t = threadIdx.x;
  if(b<16){
    const float* sr = fws + F_SR + b*CCH;
    const float* sd = fws + F_SD + b*CCH;
    for(int idx=t; idx<128*256; idx+=256){
      int c = idx & 255;
      wqs[b*32768+idx] = f2bf(qw[idx]*sr[c]);
      wks[b*32768+idx] = f2bf(kw[idx]*sd[c]);
    }
  } else {
    for(int idx=t; idx<256*256; idx+=256) vwb[idx] = f2bf(vw[idx]);
  }
}

// ============ K4: MFMA projection GEMM ============
__global__ __launch_bounds__(256) void k_gemm(const bf16* __restrict__ xT, const bf16* __restrict__ xdT,
                                              const bf16* __restrict__ xfT,
                                              const bf16* __restrict__ wqs, const bf16* __restrict__ wks,
                                              const bf16* __restrict__ vwb,
                                              float* __restrict__ fws, bf16* __restrict__ proj){
  __shared__ __align__(16) char sm[33280];
  int bid = blockIdx.x;
  int sw = (bid & 7)*784 + (bid >> 3);
  int o_t = sw & 7;
  int rest = sw >> 3;
  int s_t = rest % 49;
  int n   = rest / 49;
  int s0g = s_t*64;

  const bf16* Ag = (o_t<2 ? xT : (o_t<4 ? xdT : xfT)) + (size_t)n*SSP*CCH;
  const bf16* Wg;
  if(o_t<2)      Wg = wqs + (size_t)n*32768 + o_t*64*256;
  else if(o_t<4) Wg = wks + (size_t)n*32768 + (o_t-2)*64*256;
  else           Wg = vwb + (size_t)(o_t-4)*64*256;

  int tid = threadIdx.x;
  int w = tid>>6, lane = tid&63;
  int l15 = lane & 15, l4 = lane >> 4;

  float* sst = (float*)(sm + 32768);
  if(tid<128) sst[tid]=0.f;

  f32x4 acc[2][2];
  #pragma unroll
  for(int f=0;f<2;f++){ acc[f][0]=(f32x4){0,0,0,0}; acc[f][1]=(f32x4){0,0,0,0}; }

  auto stage = [&](int b, int kk){
    #pragma unroll
    for(int j=0;j<2;j++){
      int rowstart = w*16 + j*8;
      int row = rowstart + (lane>>3);
      int ch  = (lane&7) ^ (row&7);
      const bf16* gA = Ag + (size_t)(s0g + row)*CCH + kk*64 + ch*8;
      gl16(gA, sm + (b?8192:0) + rowstart*128);
      const bf16* gB = Wg + (size_t)row*CCH + kk*64 + ch*8;
      gl16(gB, sm + 16384 + (b?8192:0) + rowstart*128);
    }
  };

  stage(0,0);
  __syncthreads();
  int cur=0;
  int sl0 = (w&1)*32, ol0 = (w>>1)*32;
  for(int kk=0;kk<4;kk++){
    if(kk<3) stage(cur^1, kk+1);
    const short* Ab = (const short*)(sm + (cur?8192:0));
    const short* Bb = (const short*)(sm + 16384 + (cur?8192:0));
    #pragma unroll
    for(int kh=0;kh<2;kh++){
      bf16x8 a[2], b[2];
      #pragma unroll
      for(int f=0;f<2;f++){
        int sr = sl0 + f*16 + l15;
        int chv = (kh*4 + l4) ^ (sr&7);
        a[f] = *(const bf16x8*)(Ab + sr*64 + chv*8);
      }
      #pragma unroll
      for(int e=0;e<2;e++){
        int orw = ol0 + e*16 + l15;
        int chv = (kh*4 + l4) ^ (orw&7);
        b[e] = *(const bf16x8*)(Bb + orw*64 + chv*8);
      }
      #pragma unroll
      for(int f=0;f<2;f++)
        #pragma unroll
        for(int e=0;e<2;e++)
          acc[f][e] = __builtin_amdgcn_mfma_f32_16x16x32_bf16(a[f], b[e], acc[f][e], 0,0,0);
    }
    __syncthreads();
    cur ^= 1;
  }

  #pragma unroll
  for(int e=0;e<2;e++){
    float s1=0.f, s2=0.f;
    #pragma unroll
    for(int f=0;f<2;f++)
      #pragma unroll
      for(int r=0;r<4;r++){ float v=acc[f][e][r]; s1+=v; s2+=v*v; }
    s1 += __shfl_xor(s1,16); s2 += __shfl_xor(s2,16);
    s1 += __shfl_xor(s1,32); s2 += __shfl_xor(s2,32);
    if(l4==0){
      int ol = ol0 + e*16 + l15;
      atomicAdd(&sst[ol], s1);
      atomicAdd(&sst[64+ol], s2);
    }
  }
  #pragma unroll
  for(int f=0;f<2;f++)
    #pragma unroll
    for(int e=0;e<2;e++){
      int sbase = s0g + (w&1)*32 + f*16 + l4*4;
      int o = o_t*64 + ol0 + e*16 + l15;
      short4 pk;
      pk.x = f2s(acc[f][e][0]); pk.y = f2s(acc[f][e][1]);
      pk.z = f2s(acc[f][e][2]); pk.w = f2s(acc[f][e][3]);
      *reinterpret_cast<short4*>(proj + ((size_t)n*OCT + o)*SSP + sbase) = pk;
    }
  __syncthreads();
  if(tid<64){
    int og = o_t*64 + tid;
    atomicAdd(&fws[F_PSUM+og], sst[tid]);
    atomicAdd(&fws[F_PSQ+og],  sst[64+tid]);
  }
}

// ============ K5: finalize proj BN ============
__global__ void k_finproj(const float* qg,const float* qb,const float* kg,const float* kb,
                          const float* vg,const float* vb, float* fws){
  int o = threadIdx.x;
  float m = fws[F_PSUM+o]*(1.0f/CNT_PROJ);
  float var = fws[F_PSQ+o]*(1.0f/CNT_PROJ) - m*m;
  float g,b;
  if(o<128){ g=qg[o]; b=qb[o]; }
  else if(o<256){ g=kg[o-128]; b=kb[o-128]; }
  else { g=vg[o-256]; b=vb[o-256]; }
  float a = g*rsqrtf(var+EPSV);
  fws[F_PA+o]=a; fws[F_PB+o]=b-m*a;
}

// ============ Tables (16 blocks: block 0 small tables+R1, all blocks 32 R2 entries) ============
__global__ __launch_bounds__(256) void k_tables(const float* __restrict__ rel, short* __restrict__ tb,
                                                float* __restrict__ fws){
  int t = threadIdx.x, b = blockIdx.x;
  if(b==0){
    for(int idx=t; idx<112*24; idx+=256){
      int d = idx/24, c = idx - d*24;
      short vq=0, vk=0;
      if(c<16 && d<RL){ vq = f2s(rel[c*RL+d]); vk = f2s(rel[(16+c)*RL+d]); }
      tb[T_RQ+idx]=vq; tb[T_RK+idx]=vk;
    }
    for(int idx=t; idx<32*128; idx+=256){
      int c = idx>>7, d = idx&127;
      short v=0;
      if(d<RL) v = f2s(rel[(32+c)*RL+d]);
      tb[T_RV+idx]=v;
    }
    if(t<32){
      int c = t&15;
      const float* rr = rel + ((t<16)? c : 16+c)*RL;
      float* dst = fws + ((t<16)? F_R1Q : F_R1K) + c*56;
      float s=0;
      for(int d=0;d<56;d++) s += s2f(f2s(rr[d]));
      dst[0]=s;
      for(int i=1;i<56;i++){ s += s2f(f2s(rr[i+55])) - s2f(f2s(rr[i-1])); dst[i]=s; }
    }
  }
  if(t<32){
    int p = b*32 + t;
    int tensor = p>>8, c=(p>>4)&15, cp=p&15;
    const float* ra = rel + ((tensor? 16+c : c))*RL;
    const float* rb = rel + ((tensor? 16+cp : cp))*RL;
    float* dst = fws + (tensor? F_R2K : F_R2Q) + (c*16+cp)*56;
    float s=0;
    for(int d=0;d<56;d++) s += s2f(f2s(ra[d]))*s2f(f2s(rb[d]));
    dst[0]=s;
    for(int i=1;i<56;i++){
      s += s2f(f2s(ra[i+55]))*s2f(f2s(rb[i+55])) - s2f(f2s(ra[i-1]))*s2f(f2s(rb[i-1]));
      dst[i]=s;
    }
  }
}

// ============ K6: analytic sim-BN statistics (stride-60 LDS: conflict-free b64) ============
__global__ __launch_bounds__(256) void k_simstat(const bf16* __restrict__ proj,
                                                 float* __restrict__ fws){
  __shared__ __align__(16) short qs[128*60];
  __shared__ __align__(16) short ks[128*60];
  int w = blockIdx.x, n = blockIdx.y;
  int t = threadIdx.x;
  {
    int o = t;
    float pa = fws[F_PA+o], pb = fws[F_PB+o];
    const bf16* src = proj + ((size_t)n*OCT + o)*SSP + w*HH;
    short* dst = (o<128) ? &qs[o*60] : &ks[(o-128)*60];
    #pragma unroll
    for(int j=0;j<7;j++){
      bf16x8 vv = *(const bf16x8*)(src + j*8);
      s16x4 r0, r1;
      #pragma unroll
      for(int e=0;e<4;e++){ r0[e] = f2s(pa*s2f(vv[e]) + pb); r1[e] = f2s(pa*s2f(vv[4+e]) + pb); }
      *(s16x4*)(dst + j*8) = r0;
      *(s16x4*)(dst + j*8 + 4) = r1;
    }
  }
  __syncthreads();
  int g = t>>5, u = t&31;
  const short* Q = &qs[g*16*60];
  const short* K = &ks[g*16*60];
  float a0=0,a1=0,a2=0,a3=0,a4=0,a5=0;
  if(u<16){
    float qsum=0, ksum=0;
    #pragma unroll
    for(int i4=0;i4<14;i4++){
      s16x4 q4 = *(const s16x4*)(Q + u*60 + i4*4);
      s16x4 k4 = *(const s16x4*)(K + u*60 + i4*4);
      #pragma unroll
      for(int e=0;e<4;e++){ qsum += s2f(q4[e]); ksum += s2f(k4[e]); }
    }
    a0 = qsum*ksum;
  }
  const float* R2Q = fws + F_R2Q;
  const float* R2K = fws + F_R2K;
  for(int p=u; p<256; p+=32){
    int c = p>>4, cp = p&15;
    const short* qc = Q + c*60; const short* qp = Q + cp*60;
    const short* kc = K + c*60; const short* kp = K + cp*60;
    const float* r2q = R2Q + p*56;
    const float* r2k = R2K + p*56;
    float gq=0, gk=0, sq=0, sk=0;
    #pragma unroll 7
    for(int i4=0;i4<14;i4++){
      s16x4 qc4 = *(const s16x4*)(qc + i4*4);
      s16x4 qp4 = *(const s16x4*)(qp + i4*4);
      s16x4 kc4 = *(const s16x4*)(kc + i4*4);
      s16x4 kp4 = *(const s16x4*)(kp + i4*4);
      float4 rq = *(const float4*)(r2q + i4*4);
      float4 rk = *(const float4*)(r2k + i4*4);
      float rqv[4] = {rq.x,rq.y,rq.z,rq.w};
      float rkv[4] = {rk.x,rk.y,rk.z,rk.w};
      #pragma unroll
      for(int e=0;e<4;e++){
        float qq = s2f(qc4[e])*s2f(qp4[e]);
        float kk = s2f(kc4[e])*s2f(kp4[e]);
        gq += qq; gk += kk;
        sq = fmaf(qq, rqv[e], sq);
        sk = fmaf(kk, rkv[e], sk);
      }
    }
    a1 += gq*gk; a3 += sq; a5 += sk;
  }
  const float* R1Q = fws + F_R1Q;
  const float* R1K = fws + F_R1K;
  for(int c=0;c<16;c++){
    for(int i=u;i<56;i+=32){
      a2 = fmaf(s2f(Q[c*60+i]), R1Q[c*56+i], a2);
      a4 = fmaf(s2f(K[c*60+i]), R1K[c*56+i], a4);
    }
  }
  #pragma unroll
  for(int m=1;m<32;m<<=1){
    a0+=__shfl_xor(a0,m); a1+=__shfl_xor(a1,m); a2+=__shfl_xor(a2,m);
    a3+=__shfl_xor(a3,m); a4+=__shfl_xor(a4,m); a5+=__shfl_xor(a5,m);
  }
  if(u==0){
    atomicAdd(&fws[F_SSUM+g],    a0); atomicAdd(&fws[F_SSQ+g],    a1);
    atomicAdd(&fws[F_SSUM+8+g],  a2); atomicAdd(&fws[F_SSQ+8+g],  a3);
    atomicAdd(&fws[F_SSUM+16+g], a4); atomicAdd(&fws[F_SSQ+16+g], a5);
  }
}

__global__ void k_finsim(const float* sg, const float* sb, float* fws){
  int ch = threadIdx.x; if(ch>=24) return;
  float m = fws[F_SSUM+ch]*(1.0f/CNT_SIM);
  float var = fws[F_SSQ+ch]*(1.0f/CNT_SIM) - m*m;
  float a = sg[ch]*rsqrtf(var+EPSV);
  fws[F_SA+ch]=a; fws[F_SB+ch]=sb[ch]-m*a;
}

// ============ K7: main MFMA attention pass ============
__global__ __launch_bounds__(512) void k_att(const bf16* __restrict__ proj,
                                             const short* __restrict__ tb,
                                             float* __restrict__ fws,
                                             bf16* __restrict__ svw, bf16* __restrict__ svew){
  __shared__ __align__(16) char sm[SMSZ];
  int g = blockIdx.x, w = blockIdx.y, n = blockIdx.z;
  int tid = threadIdx.x;
  int W = tid >> 6, lane = tid & 63;
  int l15 = lane & 15, l4 = lane >> 4;
  short* qA = (short*)(sm + OFF_QA);
  short* kA = (short*)(sm + OFF_KA);
  short* qrT = (short*)(sm + OFF_QR);   // [112][58]: (d, i)
  short* krT = (short*)(sm + OFF_KR);   // [112][58]: (d, j)
  short* vB  = (short*)(sm + OFF_VB);
  float2* red = (float2*)(sm + OFF_RED);
  float* facL = (float*)(sm + OFF_FAC);
  const short* rqB = tb + T_RQ;
  const short* rkB = tb + T_RK;
  const short* rvBg = tb + T_RV;
  const float* PA = fws + F_PA;
  const float* PB = fws + F_PB;
  const bf16x8 z8 = {};

  float aqk = fws[F_SA+g], aqr = fws[F_SA+8+g], akr = fws[F_SA+16+g];
  float bsum = fws[F_SB+g]+fws[F_SB+8+g]+fws[F_SB+16+g];

  // ---- P1: load q,k,v rows (vectorized), BN affine, pack into LDS ----
  if(tid<128) ((float*)(sm+OFF_OST))[tid]=0.f;
  if(tid<448){
    int rid = tid/7, ch = tid - rid*7;
    int o, c, isV=0;
    if(rid<16){ c=rid; o = g*GPH + c; }
    else if(rid<32){ c=rid-16; o = 128 + g*GPH + c; }
    else { c=rid-32; o = 256 + g*GPF + c; isV=1; }
    float pa = PA[o], pb = PB[o];
    const bf16* src = proj + ((size_t)n*OCT + o)*SSP + w*HH + ch*8;
    bf16x8 vv = *(const bf16x8*)src;
    bf16x8 rv;
    #pragma unroll
    for(int e=0;e<8;e++) rv[e] = f2s(pa*s2f(vv[e])+pb);
    if(!isV){
      short* dst = (rid<16)? qA : kA;
      #pragma unroll
      for(int e=0;e<8;e++) dst[(ch*8+e)*STQ + c] = rv[e];
    } else {
      *(bf16x8*)(vB + c*STA + ch*8) = rv;
      if(ch==0){
        *(bf16x8*)(vB + c*STA + 56) = z8;
        *(bf16x8*)(vB + c*STA + 64) = z8;
      }
    }
  } else {
    int z = tid-448;
    if(z<48){
      short* arr = (z<24)? qA : kA;
      int zz = (z<24)? z : z-24;
      *(int4*)((char*)arr + 56*STQ*2 + zz*16) = (int4){0,0,0,0};
    }
  }
  __syncthreads();

  // ---- P2a: QRskT[d][i], KRskT[d][j] via MFMA, packed u32-pair writes ----
  for(int T=W; T<56; T+=8){
    int isK = (T>=28);
    int t2 = isK ? T-28 : T;
    int ti = t2/7, td = t2-7*ti;
    int i0 = ti*16, d0 = td*16;
    const short* aBase = isK ? kA : qA;
    const short* bBase = isK ? rkB : rqB;
    bf16x8 av = (l4<2)? *(const bf16x8*)(aBase + (i0+l15)*STQ + l4*8) : z8;
    bf16x8 bv = (l4<2)? *(const bf16x8*)(bBase + (d0+l15)*24 + l4*8) : z8;
    f32x4 acc = {0.f,0.f,0.f,0.f};
    acc = __builtin_amdgcn_mfma_f32_16x16x32_bf16(av, bv, acc, 0,0,0);
    short* dst = isK ? krT : qrT;
    int d = d0 + l15;
    int ib = i0 + l4*4;
    if(ib < 53){   // rows ib..ib+3 all < 56
      unsigned* wp = (unsigned*)(dst + d*SQT + ib);
      wp[0] = pk2(acc[0], acc[1]);
      wp[1] = pk2(acc[2], acc[3]);
    }
  }
  __syncthreads();

  // ---- P2b: QK tiles + skew-gather + per-tile softmax partials (e kept in f32 regs) ----
  float e8[8];
  #pragma unroll
  for(int tt=0; tt<2; tt++){
    int T = W + 8*tt;
    int ti = T>>2, tj = T&3;
    int i0 = ti*16, j0 = tj*16;
    bf16x8 av = (l4<2)? *(const bf16x8*)(qA + (i0+l15)*STQ + l4*8) : z8;
    bf16x8 bv = (l4<2)? *(const bf16x8*)(kA + (j0+l15)*STQ + l4*8) : z8;
    f32x4 acc = {0.f,0.f,0.f,0.f};
    acc = __builtin_amdgcn_mfma_f32_16x16x32_bf16(av, bv, acc, 0,0,0);
    int j = j0 + l15;
    int jv = (j < HH);
    #pragma unroll
    for(int r=0;r<4;r++){
      int i = i0 + l4*4 + r;
      float vqr = s2f(qrT[(i-j+55)*SQT + i]);
      float vkr = s2f(krT[(j-i+55)*SQT + j]);
      float v = aqk*acc[r] + aqr*vqr + akr*vkr + bsum;
      float vm = jv ? v : -3.0e38f;
      float m = vm;
      #pragma unroll
      for(int msk=1; msk<16; msk<<=1) m = fmaxf(m, __shfl_xor(m, msk));
      float e = jv ? __expf(v - m) : 0.f;
      float s = e;
      #pragma unroll
      for(int msk=1; msk<16; msk<<=1) s += __shfl_xor(s, msk);
      e8[tt*4+r] = e;
      if(l15==0) red[i*4 + tj] = make_float2(m, s);
    }
  }
  __syncthreads();

  // ---- P3a: bulk-zero sim region + per-(row,tj) softmax combine factors ----
  for(int idx=tid; idx<ZERO_I4; idx+=512) ((int4*)sm)[idx] = (int4){0,0,0,0};
  if(tid<224){
    int row = tid>>2, tj = tid&3;
    float2 a0=red[row*4+0], a1=red[row*4+1], a2=red[row*4+2], a3=red[row*4+3];
    float M = fmaxf(fmaxf(a0.x,a1.x), fmaxf(a2.x,a3.x));
    float S = a0.y*__expf(a0.x-M) + a1.y*__expf(a1.x-M)
            + a2.y*__expf(a2.x-M) + a3.y*__expf(a3.x-M);
    float2 mo = (tj==0)?a0:((tj==1)?a1:((tj==2)?a2:a3));
    facL[tid] = __expf(mo.x - M)/S;
  }
  __syncthreads();

  // ---- P3b: scale + scatter sim ----
  short* simA = (short*)(sm + OFF_SIMA);
  short* simSh = (short*)(sm + OFF_SIMSH);
  #pragma unroll
  for(int tt=0; tt<2; tt++){
    int T = W + 8*tt;
    int ti = T>>2, tj = T&3;
    int j = tj*16 + l15;
    #pragma unroll
    for(int r=0;r<4;r++){
      int i = ti*16 + l4*4 + r;
      if(i<HH && j<HH){
        float p = e8[tt*4+r] * facL[i*4+tj];
        short pv = f2s(p);
        simA[i*STA + j] = pv;
        simSh[i*STSH + (i+55-j)] = pv;
      }
    }
  }
  __syncthreads();

  // ---- P4/P5: SV and SVE ----
  float* ostS = (float*)(sm + OFF_OST);
  float* ostQ = ostS + 64;
  for(int T=W; T<16; T+=8){
    int isE = (T>=8);
    int tt = T&7;
    int ti = tt>>1, tc = tt&1;
    int i0 = ti*16, c0 = tc*16;
    f32x4 acc = {0.f,0.f,0.f,0.f};
    if(!isE){
      #pragma unroll
      for(int ks=0; ks<2; ks++){
        int j0 = ks*32;
        bf16x8 av = *(const bf16x8*)(simA + (i0+l15)*STA + j0 + l4*8);
        bf16x8 bv = *(const bf16x8*)(vB + (c0+l15)*STA + j0 + l4*8);
        acc = __builtin_amdgcn_mfma_f32_16x16x32_bf16(av, bv, acc, 0,0,0);
      }
    } else {
      #pragma unroll
      for(int ks=0; ks<4; ks++){
        int d0 = ks*32;
        bf16x8 av = *(const bf16x8*)(simSh + (i0+l15)*STSH + d0 + l4*8);
        bf16x8 bv = *(const bf16x8*)(rvBg + (c0+l15)*128 + d0 + l4*8);
        acc = __builtin_amdgcn_mfma_f32_16x16x32_bf16(av, bv, acc, 0,0,0);
      }
    }
    int c = c0 + l15;
    int ib = i0 + l4*4;
    float s1=0.f, s2=0.f;
    if(ib+3 < HH){
      size_t gb = ((((size_t)n*WW + w)*GG + g)*GPF + c)*HH;
      bf16* dst = isE ? svew : svw;
      short4 pk;
      pk.x = f2s(acc[0]); pk.y = f2s(acc[1]); pk.z = f2s(acc[2]); pk.w = f2s(acc[3]);
      *reinterpret_cast<short4*>(dst + gb + ib) = pk;
      #pragma unroll
      for(int r=0;r<4;r++){ s1 += acc[r]; s2 += acc[r]*acc[r]; }
    }
    int u = 2*c + (isE?1:0);
    atomicAdd(&ostS[u], s1);
    atomicAdd(&ostQ[u], s2);
  }
  __syncthreads();
  if(tid<64){
    atomicAdd(&fws[F_OSUM + g*64 + tid], ostS[tid]);
    atomicAdd(&fws[F_OSQ  + g*64 + tid], ostQ[tid]);
  }
}

__global__ void k_finout(const float* og, const float* ob, float* fws){
  int o = threadIdx.x;
  float m = fws[F_OSUM+o]*(1.0f/CNT_PROJ);
  float var = fws[F_OSQ+o]*(1.0f/CNT_PROJ) - m*m;
  float a = og[o]*rsqrtf(var+EPSV);
  fws[F_OA+o]=a; fws[F_OB+o]=ob[o]-m*a;
}

__global__ __launch_bounds__(256) void k_out(const bf16* __restrict__ svw, const bf16* __restrict__ svew,
                                             const float* __restrict__ fws, float* __restrict__ out){
  int oc = blockIdx.x, n = blockIdx.y;
  int g = oc>>5, c = oc&31;
  __shared__ float s1l[WW][57], s2l[WW][57];
  int t=threadIdx.x;
  for(int idx=t; idx<392; idx+=256){
    int w = idx/7, hc = idx-w*7;
    size_t base = (((size_t)(n*WW+w)*GG+g)*GPF+c)*HH + hc*8;
    bf16x8 v1 = *(const bf16x8*)(svw+base);
    bf16x8 v2 = *(const bf16x8*)(svew+base);
    #pragma unroll
    for(int e=0;e<8;e++){
      s1l[w][hc*8+e] = s2f(v1[e]);
      s2l[w][hc*8+e] = s2f(v2[e]);
    }
  }
  int ch0 = g*64+2*c;
  float a1=fws[F_OA+ch0], b1=fws[F_OB+ch0], a2=fws[F_OA+ch0+1], b2=fws[F_OB+ch0+1];
  __syncthreads();
  size_t obase = (size_t)(n*CCH+oc)*SSP;
  for(int idx=t; idx<784; idx+=256){
    int h = idx/14, w4 = (idx-h*14)*4;
    float4 o4;
    o4.x = a1*s1l[w4+0][h]+b1 + a2*s2l[w4+0][h]+b2;
    o4.y = a1*s1l[w4+1][h]+b1 + a2*s2l[w4+1][h]+b2;
    o4.z = a1*s1l[w4+2][h]+b1 + a2*s2l[w4+2][h]+b2;
    o4.w = a1*s1l[w4+3][h]+b1 + a2*s2l[w4+3][h]+b2;
    *reinterpret_cast<float4*>(out + obase + (size_t)h*WW + w4) = o4;
  }
}

extern "C" void kernel_launch(void* const* d_in, const int* in_sizes, int n_in,
                              void* d_out, int out_size, void* d_ws, size_t ws_size,
                              hipStream_t stream) {
  const float* x    = (const float*)d_in[0];
  const float* xd   = (const float*)d_in[1];
  const float* carw = (const float*)d_in[2];
  const float* carb = (const float*)d_in[3];
  const float* cadw = (const float*)d_in[4];
  const float* cadb = (const float*)d_in[5];
  const float* qw   = (const float*)d_in[6];
  const float* kw   = (const float*)d_in[7];
  const float* vw   = (const float*)d_in[8];
  const float* bnqg = (const float*)d_in[9];
  const float* bnqb = (const float*)d_in[10];
  const float* bnkg = (const float*)d_in[11];
  const float* bnkb = (const float*)d_in[12];
  const float* bnvg = (const float*)d_in[13];
  const float* bnvb = (const float*)d_in[14];
  const float* bnsg = (const float*)d_in[15];
  const float* bnsb = (const float*)d_in[16];
  const float* bnog = (const float*)d_in[17];
  const float* bnob = (const float*)d_in[18];
  const float* rel  = (const float*)d_in[19];
  float* out = (float*)d_out;

  char* ws = (char*)d_ws;
  const size_t PROJ_BYTES = (size_t)NN*OCT*SSP*sizeof(bf16);
  const size_t XT_BYTES   = (size_t)NN*SSP*CCH*sizeof(bf16);
  const size_t WQS_BYTES  = (size_t)NN*128*256*sizeof(bf16);
  const size_t VWB_BYTES  = (size_t)256*256*sizeof(bf16);
  const size_t FWS_BYTES  = (size_t)F_TOT*sizeof(float);
  const size_t TB_BYTES   = (size_t)((T_TOT+7)/8*8)*sizeof(short);

  size_t off = 0;
  bf16* proj = (bf16*)(ws + off); off += PROJ_BYTES;
  bf16* xT   = (bf16*)(ws + off); size_t off_xT = off; off += XT_BYTES;
  bf16* xdT  = (bf16*)(ws + off); size_t off_xdT = off; off += XT_BYTES;
  bf16* xfT  = (bf16*)(ws + off); off += XT_BYTES;
  bf16* wqs  = (bf16*)(ws + off); off += WQS_BYTES;
  bf16* wks  = (bf16*)(ws + off); off += WQS_BYTES;
  bf16* vwb  = (bf16*)(ws + off); off += VWB_BYTES;
  float* fws = (float*)(ws + off); off += FWS_BYTES;
  short* tb  = (short*)(ws + off); off += TB_BYTES;
  if (ws_size < off) return;
  bf16* svw  = (bf16*)(ws + off_xT);
  bf16* svew = (bf16*)(ws + off_xdT);

  hipMemsetAsync(fws, 0, (size_t)F_ACC_END*sizeof(float), stream);
  k_prep<<<dim3(98,NN), 256, 0, stream>>>(x, xd, fws, xT, xdT, xfT);
  k_chanatt<<<NN, 256, 0, stream>>>(carw, carb, cadw, cadb, fws);
  k_wprep<<<17, 256, 0, stream>>>(qw, kw, vw, fws, wqs, wks, vwb);
  k_tables<<<16, 256, 0, stream>>>(rel, tb, fws);
  k_gemm<<<dim3(6272), 256, 0, stream>>>(xT, xdT, xfT, wqs, wks, vwb, fws, proj);
  k_finproj<<<1, 512, 0, stream>>>(bnqg,bnqb,bnkg,bnkb,bnvg,bnvb, fws);
  k_simstat<<<dim3(WW,NN), 256, 0, stream>>>(proj, fws);
  k_finsim<<<1, 32, 0, stream>>>(bnsg, bnsb, fws);
  k_att<<<dim3(GG,WW,NN), 512, 0, stream>>>(proj, tb, fws, svw, svew);
  k_finout<<<1, 512, 0, stream>>>(bnog, bnob, fws);
  k_out<<<dim3(CCH,NN), 256, 0, stream>>>(svw, svew, fws, out);
}